// Round 10
// baseline (8059.684 us; speedup 1.0000x reference)
//
#include <hip/hip_runtime.h>
#include <cstddef>
#include <cstdint>

// VQ-VAE 1D forward — full fp32 pipeline.
// Codes: reference argmin follows fp32 dist = fl(zsq+csq) - fl(2*zc), first-index ties.
// vq_tiled is BYTE-IDENTICAL to the r7-passing kernel. conv3 per-output FMA chains keep
// the exact r7/r8/r9 expression and ic-order (retile is chain-preserving).
// R10: conv3_gn o-tile 128 x t-tile 256 (four bank-safe 64-quarters/lane, n=16):
// 384 FMA per 14 LDS instrs -> FMA-bound. __launch_bounds__(256,2) for 128 acc regs.
// d_out: x_hat (B,T,36) | codes as float (B,512) | [loss_vq, perplexity, loss_pos, loss_dir]

#define TID ((int)threadIdx.x)
#define NB 32  // whole batch, single pass

__device__ __forceinline__ float silu_f(float y) { return y / (1.f + expf(-y)); }

// ================= weight prep =================
__global__ void perm_oik_iko(const float* __restrict__ src, float* __restrict__ dst,
                             int R, int O, int I, int K) {
  int n = R * O * I * K;
  for (int idx = blockIdx.x * blockDim.x + TID; idx < n; idx += gridDim.x * blockDim.x) {
    int o = idx % O;
    int k = (idx / O) % K;
    int i = (idx / (O * K)) % I;
    int r = idx / (O * K * I);
    dst[idx] = src[((r * O + o) * I + i) * K + k];
  }
}

__global__ void perm_decout(const float* __restrict__ src, float* __restrict__ dst) {
  int n = 256 * 36 * 4;
  for (int idx = blockIdx.x * blockDim.x + TID; idx < n; idx += gridDim.x * blockDim.x) {
    int k = idx & 3;
    int o = (idx >> 2) % 36;
    int i = idx / 144;
    dst[idx] = (k < 3) ? src[(o * 256 + i) * 3 + k] : 0.f;
  }
}

__global__ void zero_k(float* p, int n) {
  int i = blockIdx.x * blockDim.x + TID;
  if (i < n) p[i] = 0.f;
}

// csq[j] = fp32 sequential sum of fl(c*c)
__global__ void csq_f32(const float* __restrict__ cb, float* __restrict__ csq) {
  int j = blockIdx.x * blockDim.x + TID;
  if (j < 1024) {
    float s = 0.f;
    for (int c = 0; c < 128; c++) { float v = cb[j * 128 + c]; s += v * v; }
    csq[j] = s;
  }
}

// ================= GroupNorm stats (apply fused into conv3) =================
__global__ __launch_bounds__(256) void gn_part_f32(const float* __restrict__ in, float* __restrict__ part) {
  int bg = blockIdx.x >> 2, q = blockIdx.x & 3;
  const float4* src = (const float4*)(in + ((size_t)bg << 16) + ((size_t)q << 14));
  float s1 = 0.f, s2 = 0.f;
  for (int f = TID; f < 4096; f += 256) {
    float4 v = src[f];
    s1 += v.x + v.y + v.z + v.w;
    s2 += v.x * v.x + v.y * v.y + v.z * v.z + v.w * v.w;
  }
  __shared__ float r1[256], r2[256];
  r1[TID] = s1; r2[TID] = s2;
  __syncthreads();
  for (int st = 128; st > 0; st >>= 1) {
    if (TID < st) { r1[TID] += r1[TID + st]; r2[TID] += r2[TID + st]; }
    __syncthreads();
  }
  if (TID == 0) { part[blockIdx.x * 2] = r1[0]; part[blockIdx.x * 2 + 1] = r2[0]; }
}

// ================= fp32 convs =================
// input conv 36->256, k=3. grid=(NB*32,4)
__global__ __launch_bounds__(256) void conv_in_k(const float* __restrict__ x, const float* __restrict__ wT,
                                                 const float* __restrict__ bias, float* __restrict__ out) {
  int b = blockIdx.x >> 5;
  int t0 = (blockIdx.x & 31) << 6;
  int o0 = blockIdx.y << 6;
  int tx = TID & 15, oy = TID >> 4;
  __shared__ float ins[36][68];
  __shared__ float wsl[36 * 192];
  for (int idx = TID; idx < 36 * 66; idx += 256) {
    int i = idx % 36, c = idx / 36;
    int t = t0 - 1 + c;
    float v = 0.f;
    if (t >= 0 && t < 2048) v = x[((size_t)(b * 2048 + t)) * 36 + i];
    ins[i][c] = v;
  }
  for (int idx = TID; idx < 36 * 192; idx += 256) {
    int o = idx & 63;
    int kk = (idx >> 6) % 3;
    int i = idx / 192;
    wsl[idx] = wT[(i * 3 + kk) * 256 + o0 + o];
  }
  __syncthreads();
  float acc[4][4];
#pragma unroll
  for (int m = 0; m < 4; m++)
#pragma unroll
    for (int n = 0; n < 4; n++) acc[m][n] = 0.f;
  for (int i = 0; i < 36; i++) {
    float xv[6];
    float4 x4 = *(const float4*)&ins[i][tx << 2];
    xv[0] = x4.x; xv[1] = x4.y; xv[2] = x4.z; xv[3] = x4.w;
    xv[4] = ins[i][(tx << 2) + 4];
    xv[5] = ins[i][(tx << 2) + 5];
    const float* wrow = &wsl[i * 192];
    float wv[3][4];
    *(float4*)wv[0] = *(const float4*)&wrow[oy << 2];
    *(float4*)wv[1] = *(const float4*)&wrow[64 + (oy << 2)];
    *(float4*)wv[2] = *(const float4*)&wrow[128 + (oy << 2)];
#pragma unroll
    for (int m = 0; m < 4; m++)
#pragma unroll
      for (int n = 0; n < 4; n++)
        acc[m][n] += wv[0][m] * xv[n] + wv[1][m] * xv[n + 1] + wv[2][m] * xv[n + 2];
  }
  int obase = o0 + (oy << 2);
#pragma unroll
  for (int m = 0; m < 4; m++) {
    int o = obase + m;
    float bv = bias[o];
    size_t rowo = (((size_t)((b << 8) + o)) << 11) + t0 + (tx << 2);
#pragma unroll
    for (int n = 0; n < 4; n++) out[rowo + n] = acc[m][n] + bv;
  }
}

// k=3 conv 256->256 with fused GN+SiLU input. o-tile 128 (two 64-halves),
// t-tile 256 (four 64-quarters/lane), ic-chunk 16. grid=(NB*8, 2).
// Per-output FMA chain identical to r7/r8/r9 (same expression, ic ascending).
__global__ __launch_bounds__(256, 2) void conv3_gn_k(const float* __restrict__ in, const float* __restrict__ part,
                                                     const float* __restrict__ gamma, const float* __restrict__ beta,
                                                     const float* __restrict__ wT, const float* __restrict__ bias,
                                                     const float* __restrict__ src, float* __restrict__ out) {
  int b = blockIdx.x >> 3;
  int t0 = (blockIdx.x & 7) << 8;
  int o0 = blockIdx.y << 7;
  int tx = TID & 15, oy = TID >> 4;
  __shared__ float ins[16][264];     // 260 used
  __shared__ float wsl[3 * 16 * 128];
  float acc[2][4][16];
#pragma unroll
  for (int h = 0; h < 2; h++)
#pragma unroll
    for (int m = 0; m < 4; m++)
#pragma unroll
      for (int n = 0; n < 16; n++) acc[h][m][n] = 0.f;
  for (int ic0 = 0; ic0 < 256; ic0 += 16) {
    int g = ic0 >> 5;
    const float* pp = part + ((size_t)((b << 3) + g)) * 8;
    float s1 = pp[0] + pp[2] + pp[4] + pp[6];
    float s2 = pp[1] + pp[3] + pp[5] + pp[7];
    float mu = s1 * (1.f / 65536.f);
    float var = s2 * (1.f / 65536.f) - mu * mu;
    float rs = rsqrtf(var + 1e-5f);
    __syncthreads();
    // stage x: row r = oy (16 rows), 16 lanes per row, per-row constants hoisted
    {
      int ch = ic0 + oy;
      float a = rs * gamma[ch];
      float bb = beta[ch] - mu * a;
      const float* grow = in + (((size_t)((b << 8) + ch)) << 11);
#pragma unroll
      for (int q = 0; q < 17; q++) {
        int c = tx + (q << 4);
        if (c < 260) {
          int t = t0 - 1 + c;
          float v = 0.f;
          if (t >= 0 && t < 2048) {
            float h = grow[t];
            float y = h * a + bb;
            v = y / (1.f + expf(-y));
          }
          ins[oy][c] = v;
        }
      }
    }
    // stage w: layout wsl[(kk*16+i)*128 + o], 1536 float4s
    for (int idx4 = TID; idx4 < 1536; idx4 += 256) {
      int o4 = (idx4 & 31) << 2;
      int i = (idx4 >> 5) & 15;
      int kk = idx4 >> 9;
      *(float4*)&wsl[(((kk << 4) + i) << 7) + o4] =
          *(const float4*)&wT[((ic0 + i) * 3 + kk) * 256 + o0 + o4];
    }
    __syncthreads();
    for (int i = 0; i < 16; i++) {
      float xq[4][6];
#pragma unroll
      for (int q = 0; q < 4; q++) {
        *(float4*)&xq[q][0] = *(const float4*)&ins[i][(q << 6) + (tx << 2)];
        *(float2*)&xq[q][4] = *(const float2*)&ins[i][(q << 6) + (tx << 2) + 4];
      }
      float wv[3][4], wb[3][4];
#pragma unroll
      for (int kk = 0; kk < 3; kk++) {
        const float* wrow = &wsl[((kk << 4) + i) << 7];
        *(float4*)wv[kk] = *(const float4*)&wrow[oy << 2];
        *(float4*)wb[kk] = *(const float4*)&wrow[64 + (oy << 2)];
      }
#pragma unroll
      for (int m = 0; m < 4; m++)
#pragma unroll
        for (int q = 0; q < 4; q++)
#pragma unroll
          for (int n = 0; n < 4; n++) {
            acc[0][m][(q << 2) + n] += wv[0][m] * xq[q][n] + wv[1][m] * xq[q][n + 1] + wv[2][m] * xq[q][n + 2];
            acc[1][m][(q << 2) + n] += wb[0][m] * xq[q][n] + wb[1][m] * xq[q][n + 1] + wb[2][m] * xq[q][n + 2];
          }
    }
  }
#pragma unroll
  for (int h = 0; h < 2; h++)
#pragma unroll
    for (int m = 0; m < 4; m++) {
      int o = o0 + (h << 6) + (oy << 2) + m;
      float bv = bias[o];
      size_t rowbase = (((size_t)((b << 8) + o)) << 11) + t0 + (tx << 2);
#pragma unroll
      for (int q = 0; q < 4; q++) {
        size_t row = rowbase + (q << 6);
#pragma unroll
        for (int n = 0; n < 4; n++) {
          float v = acc[h][m][(q << 2) + n] + bv;
          if (src) v += src[row + n];
          out[row + n] = v;
        }
      }
    }
}

// down conv k=8 stride 4, Tout=512. grid=(NB*8,4)
__global__ __launch_bounds__(256) void conv_down_k(const float* __restrict__ in, const float* __restrict__ wT,
                                                   const float* __restrict__ bias, float* __restrict__ out) {
  int b = blockIdx.x >> 3;
  int to0 = (blockIdx.x & 7) << 6;
  int o0 = blockIdx.y << 6;
  int tx = TID & 15, oy = TID >> 4;
  __shared__ float ins[16][264];
  __shared__ float wsl[16 * 512];
  float acc[4][4];
#pragma unroll
  for (int m = 0; m < 4; m++)
#pragma unroll
    for (int n = 0; n < 4; n++) acc[m][n] = 0.f;
  for (int ic0 = 0; ic0 < 256; ic0 += 16) {
    __syncthreads();
    for (int idx = TID; idx < 16 * 260; idx += 256) {
      int r = idx / 260, c = idx % 260;
      int s = (to0 << 2) - 2 + c;
      float v = 0.f;
      if (s >= 0 && s < 2048) v = in[(((size_t)((b << 8) + ic0 + r)) << 11) + s];
      ins[r][c] = v;
    }
    for (int idx = TID; idx < 16 * 512; idx += 256) {
      int o = idx & 63;
      int kk = (idx >> 6) & 7;
      int i = idx >> 9;
      wsl[idx] = wT[((ic0 + i) * 8 + kk) * 256 + o0 + o];
    }
    __syncthreads();
#pragma unroll 2
    for (int i = 0; i < 16; i++) {
      float xv[20];
#pragma unroll
      for (int q = 0; q < 5; q++) *(float4*)&xv[q * 4] = *(const float4*)&ins[i][(tx << 4) + (q << 2)];
      float wv[8][4];
#pragma unroll
      for (int kk = 0; kk < 8; kk++) *(float4*)wv[kk] = *(const float4*)&wsl[(i << 9) + (kk << 6) + (oy << 2)];
#pragma unroll
      for (int n = 0; n < 4; n++)
#pragma unroll
        for (int kk = 0; kk < 8; kk++) {
          float xval = xv[(n << 2) + kk];
#pragma unroll
          for (int m = 0; m < 4; m++) acc[m][n] += wv[kk][m] * xval;
        }
    }
  }
  int obase = o0 + (oy << 2);
#pragma unroll
  for (int m = 0; m < 4; m++) {
    int o = obase + m;
    float bv = bias[o];
    size_t rowo = (((size_t)((b << 8) + o)) << 9) + to0 + (tx << 2);
#pragma unroll
    for (int n = 0; n < 4; n++) out[rowo + n] = acc[m][n] + bv;
  }
}

// 1x1 conv, T=512. grid=(NB*8, O/64)
__global__ __launch_bounds__(256) void conv1x1_k(const float* __restrict__ in, const float* __restrict__ wIO,
                                                 const float* __restrict__ bias, float* __restrict__ out,
                                                 int Kc, int O) {
  int b = blockIdx.x >> 3;
  int t0 = (blockIdx.x & 7) << 6;
  int o0 = blockIdx.y << 6;
  int tx = TID & 15, oy = TID >> 4;
  __shared__ float xs[32][64];
  __shared__ float wsd[32][64];
  float acc[4][4];
#pragma unroll
  for (int m = 0; m < 4; m++)
#pragma unroll
    for (int n = 0; n < 4; n++) acc[m][n] = 0.f;
  for (int ic0 = 0; ic0 < Kc; ic0 += 32) {
    __syncthreads();
    for (int idx = TID; idx < 2048; idx += 256) {
      int r = idx >> 6, c = idx & 63;
      xs[r][c] = in[((size_t)(b * Kc + ic0 + r) << 9) + t0 + c];
      wsd[r][c] = wIO[(ic0 + r) * O + o0 + c];
    }
    __syncthreads();
#pragma unroll 8
    for (int i = 0; i < 32; i++) {
      float4 xvv = *(const float4*)&xs[i][tx << 2];
      float4 wvv = *(const float4*)&wsd[i][oy << 2];
      float xv[4] = {xvv.x, xvv.y, xvv.z, xvv.w};
      float wv[4] = {wvv.x, wvv.y, wvv.z, wvv.w};
#pragma unroll
      for (int m = 0; m < 4; m++)
#pragma unroll
        for (int n = 0; n < 4; n++) acc[m][n] += wv[m] * xv[n];
    }
  }
#pragma unroll
  for (int m = 0; m < 4; m++) {
    int o = o0 + (oy << 2) + m;
    float bv = bias[o];
    size_t rowo = ((size_t)(b * O + o) << 9) + t0 + (tx << 2);
#pragma unroll
    for (int n = 0; n < 4; n++) out[rowo + n] = acc[m][n] + bv;
  }
}

// ===== VQ tiled: BYTE-IDENTICAL to r7-passing kernel — do not touch =====
__global__ __launch_bounds__(256) void vq_tiled(const float* __restrict__ zE,
                                                const float* __restrict__ cb,
                                                const float* __restrict__ csq,
                                                int* __restrict__ codes) {
  int b = blockIdx.x >> 3;
  int t0 = (blockIdx.x & 7) << 6;
  int cq = TID & 15, pq = TID >> 4;
  __shared__ float Zs[128][66];
  __shared__ float Cs[64][129];
  __shared__ float zsqs[64];
  __shared__ float bd[64][17];
  __shared__ int bix[64][17];
  for (int idx = TID; idx < 128 * 64; idx += 256) {
    int c = idx >> 6, p = idx & 63;
    Zs[c][p] = zE[((size_t)(b * 128 + c) << 9) + t0 + p];
  }
  __syncthreads();
  if (TID < 64) {
    float s = 0.f;
    for (int c = 0; c < 128; c++) { float v = Zs[c][TID]; s += v * v; }
    zsqs[TID] = s;
  }
  float best[4];
  int bidx[4];
#pragma unroll
  for (int n = 0; n < 4; n++) { best[n] = 3.4e38f; bidx[n] = 0; }
  const int j0 = cq << 2;
  for (int cg = 0; cg < 16; cg++) {
    __syncthreads();
    for (int idx = TID; idx < 64 * 128; idx += 256) {
      int j = idx >> 7, c = idx & 127;
      Cs[j][c] = cb[((cg << 6) + j) * 128 + c];
    }
    __syncthreads();
    float acc[4][4];
#pragma unroll
    for (int u = 0; u < 4; u++)
#pragma unroll
      for (int n = 0; n < 4; n++) acc[u][n] = 0.f;
    for (int c = 0; c < 128; c++) {
      float4 zv4 = *(const float4*)&Zs[c][pq << 2];
      float zv[4] = {zv4.x, zv4.y, zv4.z, zv4.w};
      float cv[4];
#pragma unroll
      for (int u = 0; u < 4; u++) cv[u] = Cs[j0 + u][c];
#pragma unroll
      for (int u = 0; u < 4; u++)
#pragma unroll
        for (int n = 0; n < 4; n++) acc[u][n] += zv[n] * cv[u];
    }
#pragma unroll
    for (int u = 0; u < 4; u++) {
      int code = (cg << 6) + j0 + u;
      float cs_ = csq[code];
#pragma unroll
      for (int n = 0; n < 4; n++) {
        float A = zsqs[(pq << 2) + n] + cs_;
        float B = 2.0f * acc[u][n];
        float d = A - B;
        if (d < best[n]) { best[n] = d; bidx[n] = code; }
      }
    }
  }
  __syncthreads();
#pragma unroll
  for (int n = 0; n < 4; n++) { bd[(pq << 2) + n][cq] = best[n]; bix[(pq << 2) + n][cq] = bidx[n]; }
  __syncthreads();
  if (TID < 64) {
    float bb = bd[TID][0];
    int bj = bix[TID][0];
    for (int q = 1; q < 16; q++) {
      float d = bd[TID][q];
      int j = bix[TID][q];
      if (d < bb || (d == bb && j < bj)) { bb = d; bj = j; }
    }
    codes[(b << 9) + t0 + TID] = bj;
  }
}

// ================= VQ bookkeeping =================
__global__ void count_k(const int* __restrict__ codes, float* __restrict__ counts) {
  int n = blockIdx.x * blockDim.x + TID;
  if (n < 16384) atomicAdd(&counts[codes[n]], 1.f);
}

__global__ __launch_bounds__(256) void gather_k(const float* __restrict__ cb, const int* __restrict__ codes,
                                                const float* __restrict__ zE, float* __restrict__ zQ,
                                                float* __restrict__ vqsum) {
  double part = 0.;
  const int total = 32 * 128 * 512;
  for (int idx = blockIdx.x * blockDim.x + TID; idx < total; idx += gridDim.x * blockDim.x) {
    int t = idx & 511;
    int c = (idx >> 9) & 127;
    int b = idx >> 16;
    int code = codes[(b << 9) + t];
    float q = cb[code * 128 + c];
    double d = (double)q - (double)zE[idx];
    zQ[idx] = q;
    part += d * d;
  }
  __shared__ double red[256];
  red[TID] = part;
  __syncthreads();
  for (int st = 128; st > 0; st >>= 1) {
    if (TID < st) red[TID] += red[TID + st];
    __syncthreads();
  }
  if (TID == 0) atomicAdd(vqsum, (float)red[0]);
}

// ================= decoder-only convs =================
__global__ __launch_bounds__(256) void conv_up_k(const float* __restrict__ in, const float* __restrict__ w,
                                                 const float* __restrict__ bias, float* __restrict__ out) {
  int b = blockIdx.x / 17;
  int s0 = (blockIdx.x % 17) << 5;
  int o0 = blockIdx.y << 6;
  int tx = TID & 15, oy = TID >> 4;
  __shared__ float ins[16][36];
  __shared__ float wsl[16 * 512];
  float acc[2][4][4];
#pragma unroll
  for (int j = 0; j < 2; j++)
#pragma unroll
    for (int m = 0; m < 4; m++)
#pragma unroll
      for (int r = 0; r < 4; r++) acc[j][m][r] = 0.f;
  for (int ic0 = 0; ic0 < 256; ic0 += 16) {
    __syncthreads();
    for (int idx = TID; idx < 16 * 34; idx += 256) {
      int r = idx / 34, c = idx % 34;
      int s = s0 - 1 + c;
      float v = 0.f;
      if (s >= 0 && s < 512) v = in[(((size_t)((b << 8) + ic0 + r)) << 9) + s];
      ins[r][c] = v;
    }
    for (int idx = TID; idx < 8192; idx += 256) {
      int rr = idx & 3;
      int o = (idx >> 2) & 63;
      int h = (idx >> 8) & 1;
      int i = idx >> 9;
      wsl[idx] = w[(((size_t)(ic0 + i)) << 11) + ((size_t)(o0 + o) << 3) + (h << 2) + rr];
    }
    __syncthreads();
#pragma unroll 2
    for (int i = 0; i < 16; i++) {
      float x0 = ins[i][2 * tx], x1 = ins[i][2 * tx + 1], x2 = ins[i][2 * tx + 2];
#pragma unroll
      for (int m = 0; m < 4; m++) {
        int om = (oy << 2) + m;
        float4 wa4 = *(const float4*)&wsl[(i << 9) + (om << 2)];
        float4 wb4 = *(const float4*)&wsl[(i << 9) + 256 + (om << 2)];
        float wa[4] = {wa4.x, wa4.y, wa4.z, wa4.w};
        float wb[4] = {wb4.x, wb4.y, wb4.z, wb4.w};
#pragma unroll
        for (int r = 0; r < 4; r++) {
          acc[0][m][r] += x1 * wa[r] + x0 * wb[r];
          acc[1][m][r] += x2 * wa[r] + x1 * wb[r];
        }
      }
    }
  }
#pragma unroll
  for (int j = 0; j < 2; j++) {
    int s1 = s0 + (tx << 1) + j;
#pragma unroll
    for (int m = 0; m < 4; m++) {
      int o = o0 + (oy << 2) + m;
      float bv = bias[o];
#pragma unroll
      for (int r = 0; r < 4; r++) {
        int t = (s1 << 2) + r - 2;
        if (t >= 0 && t < 2048) out[(((size_t)((b << 8) + o)) << 11) + t] = acc[j][m][r] + bv;
      }
    }
  }
}

__global__ __launch_bounds__(256) void conv_out_k(const float* __restrict__ in, const float* __restrict__ wP,
                                                  const float* __restrict__ bias, float* __restrict__ xhat) {
  int b = blockIdx.x >> 5;
  int t0 = (blockIdx.x & 31) << 6;
  int tx = TID & 63, oy = TID >> 6;
  __shared__ float ins[32][68];
  __shared__ float wsl[32 * 144];
  float acc[9];
#pragma unroll
  for (int m = 0; m < 9; m++) acc[m] = 0.f;
  for (int ic0 = 0; ic0 < 256; ic0 += 32) {
    __syncthreads();
    for (int idx = TID; idx < 32 * 66; idx += 256) {
      int r = idx / 66, c = idx % 66;
      int t = t0 - 1 + c;
      float v = 0.f;
      if (t >= 0 && t < 2048) v = in[(((size_t)((b << 8) + ic0 + r)) << 11) + t];
      ins[r][c] = v;
    }
    for (int idx = TID; idx < 32 * 144; idx += 256) {
      wsl[idx] = wP[ic0 * 144 + idx];
    }
    __syncthreads();
#pragma unroll 4
    for (int i = 0; i < 32; i++) {
      float x0 = ins[i][tx], x1 = ins[i][tx + 1], x2 = ins[i][tx + 2];
#pragma unroll
      for (int m = 0; m < 9; m++) {
        int o = oy * 9 + m;
        float4 wv = *(const float4*)&wsl[(i * 36 + o) << 2];
        acc[m] += wv.x * x0 + wv.y * x1 + wv.z * x2;
      }
    }
  }
  size_t orow = ((size_t)(b << 11) + t0 + tx) * 36;
#pragma unroll
  for (int m = 0; m < 9; m++) {
    int o = oy * 9 + m;
    xhat[orow + o] = acc[m] + bias[o];
  }
}

// ================= losses =================
__global__ __launch_bounds__(256) void loss_k(const float* __restrict__ x, const float* __restrict__ xh,
                                              const float* __restrict__ mask, float* __restrict__ scal) {
  float pos = 0.f, dir = 0.f, ms = 0.f;
  for (int n = blockIdx.x * blockDim.x + TID; n < 65536; n += gridDim.x * blockDim.x) {
    const float* xp = x + (size_t)n * 36;
    const float* hp = xh + (size_t)n * 36;
    float a[36], h[36];
#pragma unroll
    for (int d4 = 0; d4 < 36; d4 += 4) {
      *(float4*)&a[d4] = *(const float4*)&xp[d4];
      *(float4*)&h[d4] = *(const float4*)&hp[d4];
    }
#pragma unroll
    for (int d = 0; d < 36; d++) {
      if (d < 21 || (d >= 27 && d < 30)) {
        float df = h[d] - a[d];
        float ad = fabsf(df);
        pos += (ad < 1.f) ? 0.5f * df * df : ad - 0.5f;
      }
    }
    float mL = mask[2 * (size_t)n], mR = mask[2 * (size_t)n + 1];
    const int vb[4] = {21, 24, 30, 33};
    float mv[4] = {mL, mL, mR, mR};
#pragma unroll
    for (int v = 0; v < 4; v++) {
      int o = vb[v];
      float ax = a[o], ay = a[o + 1], az = a[o + 2];
      float hx = h[o], hy = h[o + 1], hz = h[o + 2];
      float an = sqrtf(ax * ax + ay * ay + az * az) + 1e-8f;
      float hn = sqrtf(hx * hx + hy * hy + hz * hz) + 1e-8f;
      float cs = (ax * hx + ay * hy + az * hz) / (an * hn);
      dir += (1.f - cs) * mv[v];
    }
    ms += 2.f * (mL + mR);
  }
  __shared__ float rp[256], rd[256], rm[256];
  rp[TID] = pos; rd[TID] = dir; rm[TID] = ms;
  __syncthreads();
  for (int st = 128; st > 0; st >>= 1) {
    if (TID < st) { rp[TID] += rp[TID + st]; rd[TID] += rd[TID + st]; rm[TID] += rm[TID + st]; }
    __syncthreads();
  }
  if (TID == 0) {
    atomicAdd(&scal[1], rp[0]);
    atomicAdd(&scal[2], rd[0]);
    atomicAdd(&scal[3], rm[0]);
  }
}

__global__ __launch_bounds__(256) void finalize_k(const float* __restrict__ counts, const float* __restrict__ scal,
                                                  float* __restrict__ tail) {
  __shared__ float red[256];
  float s = 0.f;
  for (int j = TID; j < 1024; j += 256) {
    float avg = counts[j] * (1.f / 16384.f);
    s += avg * logf(avg + 1e-10f);
  }
  red[TID] = s;
  __syncthreads();
  for (int st = 128; st > 0; st >>= 1) {
    if (TID < st) red[TID] += red[TID + st];
    __syncthreads();
  }
  if (TID == 0) {
    tail[0] = 1.25f * scal[0] * (1.f / 2097152.f);
    tail[1] = expf(-red[0]);
    tail[2] = scal[1] * (1.f / 65536.f);
    tail[3] = scal[2] / fmaxf(scal[3], 1.f);
  }
}

__global__ void codesf_k(const int* __restrict__ codes, float* __restrict__ o) {
  int n = blockIdx.x * blockDim.x + TID;
  if (n < 16384) o[n] = (float)codes[n];
}

// ================= host =================
extern "C" void kernel_launch(void* const* d_in, const int* in_sizes, int n_in,
                              void* d_out, int out_size, void* d_ws, size_t ws_size,
                              hipStream_t stream) {
  const float* x = (const float*)d_in[0];
  const float* mask = (const float*)d_in[1];
  const float* enc_in_w = (const float*)d_in[2];
  const float* enc_in_b = (const float*)d_in[3];
  const float* enc_gn1_g = (const float*)d_in[4];
  const float* enc_gn1_b = (const float*)d_in[5];
  const float* enc_c1_w = (const float*)d_in[6];
  const float* enc_c1_b = (const float*)d_in[7];
  const float* enc_gn2_g = (const float*)d_in[8];
  const float* enc_gn2_b = (const float*)d_in[9];
  const float* enc_c2_w = (const float*)d_in[10];
  const float* enc_c2_b = (const float*)d_in[11];
  const float* down_w = (const float*)d_in[12];
  const float* down_b = (const float*)d_in[13];
  const float* enc_out_w = (const float*)d_in[14];
  const float* enc_out_b = (const float*)d_in[15];
  const float* codebook = (const float*)d_in[16];
  const float* dec_in_w = (const float*)d_in[17];
  const float* dec_in_b = (const float*)d_in[18];
  const float* up_w = (const float*)d_in[19];
  const float* up_b = (const float*)d_in[20];
  const float* dec_gn1_g = (const float*)d_in[21];
  const float* dec_gn1_b = (const float*)d_in[22];
  const float* dec_c1_w = (const float*)d_in[23];
  const float* dec_c1_b = (const float*)d_in[24];
  const float* dec_gn2_g = (const float*)d_in[25];
  const float* dec_gn2_b = (const float*)d_in[26];
  const float* dec_c2_w = (const float*)d_in[27];
  const float* dec_c2_b = (const float*)d_in[28];
  const float* dec_out_w = (const float*)d_in[29];
  const float* dec_out_b = (const float*)d_in[30];

  char* W = (char*)d_ws;
  float* zE = (float*)(W + 0);                        // 8,388,608
  float* zQ = (float*)(W + 8388608);                  // 8,388,608
  int* codes = (int*)(W + 16777216);                  // 65,536
  float* counts = (float*)(W + 16842752);             // 4,096
  float* scal = (float*)(W + 16846848);               // 32
  float* csq = (float*)(W + 16846880);                // 4,096
  float* part_f = (float*)(W + 16850976);             // 8,192 (32 b x 8 g x 4 q x 2)
  float* wf_enc_in = (float*)(W + 16859168);          // 110,592
  float* wf_enc_c1 = (float*)(W + 16969760);          // 3,145,728
  float* wf_enc_c2 = (float*)(W + 20115488);          // 3,145,728
  float* wf_down = (float*)(W + 23261216);            // 2,097,152
  float* wf_enc_out = (float*)(W + 25358368);         // 131,072
  float* wf_dec_in = (float*)(W + 25489440);          // 131,072
  float* wf_dec_c1 = (float*)(W + 25620512);          // 3,145,728
  float* wf_dec_c2 = (float*)(W + 28766240);          // 3,145,728
  float* wf_dec_out = (float*)(W + 31911968);         // 147,456
  // big region @48MiB: f0, f2 (67.1MB each, 32 batches) + dech (16.8MB)
  float* f0 = (float*)(W + 50331648);
  float* f2 = (float*)(W + 50331648 + (size_t)67108864);
  float* dech = (float*)(W + 50331648 + 2 * (size_t)67108864);

  dim3 blk(256);
  zero_k<<<dim3(5), blk, 0, stream>>>(counts, 1032);
  perm_oik_iko<<<dim3(128), blk, 0, stream>>>(enc_in_w, wf_enc_in, 1, 256, 36, 3);
  perm_oik_iko<<<dim3(1024), blk, 0, stream>>>(enc_c1_w, wf_enc_c1, 4, 256, 256, 3);
  perm_oik_iko<<<dim3(1024), blk, 0, stream>>>(enc_c2_w, wf_enc_c2, 4, 256, 256, 3);
  perm_oik_iko<<<dim3(1024), blk, 0, stream>>>(down_w, wf_down, 1, 256, 256, 8);
  perm_oik_iko<<<dim3(128), blk, 0, stream>>>(enc_out_w, wf_enc_out, 1, 128, 256, 1);
  perm_oik_iko<<<dim3(128), blk, 0, stream>>>(dec_in_w, wf_dec_in, 1, 256, 128, 1);
  perm_oik_iko<<<dim3(1024), blk, 0, stream>>>(dec_c1_w, wf_dec_c1, 4, 256, 256, 3);
  perm_oik_iko<<<dim3(1024), blk, 0, stream>>>(dec_c2_w, wf_dec_c2, 4, 256, 256, 3);
  perm_decout<<<dim3(64), blk, 0, stream>>>(dec_out_w, wf_dec_out);
  csq_f32<<<dim3(4), blk, 0, stream>>>(codebook, csq);

  const int GN = NB * 8 * 4;  // 1024 blocks

  // ---- encoder (fp32), whole batch ----
  conv_in_k<<<dim3(NB * 32, 4), blk, 0, stream>>>(x, wf_enc_in, enc_in_b, f0);
  for (int i = 0; i < 4; i++) {
    gn_part_f32<<<dim3(GN), blk, 0, stream>>>(f0, part_f);
    conv3_gn_k<<<dim3(NB * 8, 2), blk, 0, stream>>>(f0, part_f, enc_gn1_g + i * 256, enc_gn1_b + i * 256,
                                                    wf_enc_c1 + i * 196608, enc_c1_b + i * 256, nullptr, f2);
    gn_part_f32<<<dim3(GN), blk, 0, stream>>>(f2, part_f);
    conv3_gn_k<<<dim3(NB * 8, 2), blk, 0, stream>>>(f2, part_f, enc_gn2_g + i * 256, enc_gn2_b + i * 256,
                                                    wf_enc_c2 + i * 196608, enc_c2_b + i * 256, f0, f0);
  }
  conv_down_k<<<dim3(NB * 8, 4), blk, 0, stream>>>(f0, wf_down, down_b, f2);
  conv1x1_k<<<dim3(NB * 8, 2), blk, 0, stream>>>(f2, wf_enc_out, enc_out_b, zE, 256, 128);

  // ---- quantize ----
  vq_tiled<<<dim3(256), blk, 0, stream>>>(zE, codebook, csq, codes);
  count_k<<<dim3(64), blk, 0, stream>>>(codes, counts);
  gather_k<<<dim3(512), blk, 0, stream>>>(codebook, codes, zE, zQ, &scal[0]);

  // ---- decoder (fp32), whole batch ----
  float* xhat = (float*)d_out;
  conv1x1_k<<<dim3(NB * 8, 4), blk, 0, stream>>>(zQ, wf_dec_in, dec_in_b, dech, 128, 256);
  conv_up_k<<<dim3(NB * 17, 4), blk, 0, stream>>>(dech, up_w, up_b, f0);
  for (int i = 0; i < 4; i++) {
    gn_part_f32<<<dim3(GN), blk, 0, stream>>>(f0, part_f);
    conv3_gn_k<<<dim3(NB * 8, 2), blk, 0, stream>>>(f0, part_f, dec_gn1_g + i * 256, dec_gn1_b + i * 256,
                                                    wf_dec_c1 + i * 196608, dec_c1_b + i * 256, nullptr, f2);
    gn_part_f32<<<dim3(GN), blk, 0, stream>>>(f2, part_f);
    conv3_gn_k<<<dim3(NB * 8, 2), blk, 0, stream>>>(f2, part_f, dec_gn2_g + i * 256, dec_gn2_b + i * 256,
                                                    wf_dec_c2 + i * 196608, dec_c2_b + i * 256, f0, f0);
  }
  conv_out_k<<<dim3(NB * 32), blk, 0, stream>>>(f0, wf_dec_out, dec_out_b, xhat);

  // ---- losses / scalars ----
  loss_k<<<dim3(256), blk, 0, stream>>>(x, xhat, mask, scal);
  finalize_k<<<dim3(1), blk, 0, stream>>>(counts, scal, (float*)d_out + 2375680);
  codesf_k<<<dim3(64), blk, 0, stream>>>(codes, (float*)d_out + 2359296);
}

// Round 11
// 7987.535 us; speedup vs baseline: 1.0090x; 1.0090x over previous
//
#include <hip/hip_runtime.h>
#include <cstddef>
#include <cstdint>

// VQ-VAE 1D forward — full fp32 pipeline.
// Codes: reference argmin follows fp32 dist = fl(zsq+csq) - fl(2*zc), first-index ties.
// vq_tiled is BYTE-IDENTICAL to the r7-passing kernel. conv3 per-output FMA chains keep
// the exact r7-r10 expression and ic-order.
// R11: (1) register-prefetch pipeline in conv3_gn (global latency overlapped with FMAs);
// (2) GN stats fused into producer epilogues (atomicAdd per (layer,b,group)) — gn_part
// kernels removed. Stats = whole-group sums (z_e shift ~1e-7, safe per r4-vs-r7 evidence).
// d_out: x_hat (B,T,36) | codes as float (B,512) | [loss_vq, perplexity, loss_pos, loss_dir]

#define TID ((int)threadIdx.x)
#define NB 32  // whole batch, single pass

__device__ __forceinline__ float silu_f(float y) { return y / (1.f + expf(-y)); }

// ================= weight prep =================
__global__ void perm_oik_iko(const float* __restrict__ src, float* __restrict__ dst,
                             int R, int O, int I, int K) {
  int n = R * O * I * K;
  for (int idx = blockIdx.x * blockDim.x + TID; idx < n; idx += gridDim.x * blockDim.x) {
    int o = idx % O;
    int k = (idx / O) % K;
    int i = (idx / (O * K)) % I;
    int r = idx / (O * K * I);
    dst[idx] = src[((r * O + o) * I + i) * K + k];
  }
}

__global__ void perm_decout(const float* __restrict__ src, float* __restrict__ dst) {
  int n = 256 * 36 * 4;
  for (int idx = blockIdx.x * blockDim.x + TID; idx < n; idx += gridDim.x * blockDim.x) {
    int k = idx & 3;
    int o = (idx >> 2) % 36;
    int i = idx / 144;
    dst[idx] = (k < 3) ? src[(o * 256 + i) * 3 + k] : 0.f;
  }
}

__global__ void zero_k(float* p, int n) {
  int i = blockIdx.x * blockDim.x + TID;
  if (i < n) p[i] = 0.f;
}

// csq[j] = fp32 sequential sum of fl(c*c)
__global__ void csq_f32(const float* __restrict__ cb, float* __restrict__ csq) {
  int j = blockIdx.x * blockDim.x + TID;
  if (j < 1024) {
    float s = 0.f;
    for (int c = 0; c < 128; c++) { float v = cb[j * 128 + c]; s += v * v; }
    csq[j] = s;
  }
}

// ================= fp32 convs =================
// input conv 36->256, k=3, with GN-stats epilogue. grid=(NB*32,4)
__global__ __launch_bounds__(256) void conv_in_k(const float* __restrict__ x, const float* __restrict__ wT,
                                                 const float* __restrict__ bias, float* __restrict__ out,
                                                 float* __restrict__ partOut) {
  int b = blockIdx.x >> 5;
  int t0 = (blockIdx.x & 31) << 6;
  int o0 = blockIdx.y << 6;
  int tx = TID & 15, oy = TID >> 4;
  __shared__ float ins[36][68];
  __shared__ float wsl[36 * 192];
  for (int idx = TID; idx < 36 * 66; idx += 256) {
    int i = idx % 36, c = idx / 36;
    int t = t0 - 1 + c;
    float v = 0.f;
    if (t >= 0 && t < 2048) v = x[((size_t)(b * 2048 + t)) * 36 + i];
    ins[i][c] = v;
  }
  for (int idx = TID; idx < 36 * 192; idx += 256) {
    int o = idx & 63;
    int kk = (idx >> 6) % 3;
    int i = idx / 192;
    wsl[idx] = wT[(i * 3 + kk) * 256 + o0 + o];
  }
  __syncthreads();
  float acc[4][4];
#pragma unroll
  for (int m = 0; m < 4; m++)
#pragma unroll
    for (int n = 0; n < 4; n++) acc[m][n] = 0.f;
  for (int i = 0; i < 36; i++) {
    float xv[6];
    float4 x4 = *(const float4*)&ins[i][tx << 2];
    xv[0] = x4.x; xv[1] = x4.y; xv[2] = x4.z; xv[3] = x4.w;
    xv[4] = ins[i][(tx << 2) + 4];
    xv[5] = ins[i][(tx << 2) + 5];
    const float* wrow = &wsl[i * 192];
    float wv[3][4];
    *(float4*)wv[0] = *(const float4*)&wrow[oy << 2];
    *(float4*)wv[1] = *(const float4*)&wrow[64 + (oy << 2)];
    *(float4*)wv[2] = *(const float4*)&wrow[128 + (oy << 2)];
#pragma unroll
    for (int m = 0; m < 4; m++)
#pragma unroll
      for (int n = 0; n < 4; n++)
        acc[m][n] += wv[0][m] * xv[n] + wv[1][m] * xv[n + 1] + wv[2][m] * xv[n + 2];
  }
  int obase = o0 + (oy << 2);
  float s1 = 0.f, s2 = 0.f;
#pragma unroll
  for (int m = 0; m < 4; m++) {
    int o = obase + m;
    float bv = bias[o];
    size_t rowo = (((size_t)((b << 8) + o)) << 11) + t0 + (tx << 2);
#pragma unroll
    for (int n = 0; n < 4; n++) {
      float v = acc[m][n] + bv;
      out[rowo + n] = v;
      s1 += v; s2 += v * v;
    }
  }
  // stats epilogue: group = (y<<1) | (oy>>3)
  __syncthreads();
  float* red = (float*)ins;
  red[TID] = s1; red[256 + TID] = s2;
  __syncthreads();
  for (int st = 64; st > 0; st >>= 1) {
    if ((TID & 127) < st) { red[TID] += red[TID + st]; red[256 + TID] += red[256 + TID + st]; }
    __syncthreads();
  }
  if ((TID & 127) == 0) {
    int g = (blockIdx.y << 1) + (TID >> 7);
    atomicAdd(&partOut[(((b << 3) + g) << 1)], red[TID]);
    atomicAdd(&partOut[(((b << 3) + g) << 1) + 1], red[256 + TID]);
  }
}

// k=3 conv 256->256 with fused GN+SiLU input (stats from partIn) + stats epilogue (partOut).
// o-tile 128, t-tile 256, ic-chunk 16, register-prefetch pipeline. grid=(NB*8, 2).
__global__ __launch_bounds__(256, 2) void conv3_gn_k(const float* __restrict__ in, const float* __restrict__ partIn,
                                                     const float* __restrict__ gamma, const float* __restrict__ beta,
                                                     const float* __restrict__ wT, const float* __restrict__ bias,
                                                     const float* __restrict__ src, float* __restrict__ out,
                                                     float* __restrict__ partOut) {
  int b = blockIdx.x >> 3;
  int t0 = (blockIdx.x & 7) << 8;
  int o0 = blockIdx.y << 7;
  int tx = TID & 15, oy = TID >> 4;
  __shared__ float ins[16][264];     // 260 used
  __shared__ float wsl[3 * 16 * 128];
  float acc[2][4][16];
#pragma unroll
  for (int h = 0; h < 2; h++)
#pragma unroll
    for (int m = 0; m < 4; m++)
#pragma unroll
      for (int n = 0; n < 16; n++) acc[h][m][n] = 0.f;

  float xpre[17];
  float4 wpre[6];
  // prefetch chunk 0
  {
    const float* grow = in + (((size_t)((b << 8) + oy)) << 11);
#pragma unroll
    for (int q = 0; q < 17; q++) {
      int c = tx + (q << 4);
      float v = 0.f;
      if (c < 260) {
        int t = t0 - 1 + c;
        if (t >= 0 && t < 2048) v = grow[t];
      }
      xpre[q] = v;
    }
#pragma unroll
    for (int j = 0; j < 6; j++) {
      int idx4 = TID + (j << 8);
      int o4 = (idx4 & 31) << 2;
      int i = (idx4 >> 5) & 15;
      int kk = idx4 >> 9;
      wpre[j] = *(const float4*)&wT[(i * 3 + kk) * 256 + o0 + o4];
    }
  }

  for (int ic0 = 0; ic0 < 256; ic0 += 16) {
    int g = ic0 >> 5;
    const float* pp = partIn + (((size_t)((b << 3) + g)) << 1);
    float s1 = pp[0], s2 = pp[1];
    float mu = s1 * (1.f / 65536.f);
    float var = s2 * (1.f / 65536.f) - mu * mu;
    float rs = rsqrtf(var + 1e-5f);
    int ch = ic0 + oy;
    float a = rs * gamma[ch];
    float bb = beta[ch] - mu * a;
    __syncthreads();  // previous compute done before overwriting LDS
    // write prefetched regs -> LDS (apply GN+SiLU; zero padding outside [0,2048))
#pragma unroll
    for (int q = 0; q < 17; q++) {
      int c = tx + (q << 4);
      if (c < 260) {
        int t = t0 - 1 + c;
        float v = 0.f;
        if (t >= 0 && t < 2048) {
          float y = xpre[q] * a + bb;
          v = y / (1.f + expf(-y));
        }
        ins[oy][c] = v;
      }
    }
#pragma unroll
    for (int j = 0; j < 6; j++) {
      int idx4 = TID + (j << 8);
      int o4 = (idx4 & 31) << 2;
      int i = (idx4 >> 5) & 15;
      int kk = idx4 >> 9;
      *(float4*)&wsl[(((kk << 4) + i) << 7) + o4] = wpre[j];
    }
    __syncthreads();
    // prefetch next chunk (global latency overlaps the compute below)
    if (ic0 < 240) {
      int icn = ic0 + 16;
      const float* grow = in + (((size_t)((b << 8) + icn + oy)) << 11);
#pragma unroll
      for (int q = 0; q < 17; q++) {
        int c = tx + (q << 4);
        float v = 0.f;
        if (c < 260) {
          int t = t0 - 1 + c;
          if (t >= 0 && t < 2048) v = grow[t];
        }
        xpre[q] = v;
      }
#pragma unroll
      for (int j = 0; j < 6; j++) {
        int idx4 = TID + (j << 8);
        int o4 = (idx4 & 31) << 2;
        int i = (idx4 >> 5) & 15;
        int kk = idx4 >> 9;
        wpre[j] = *(const float4*)&wT[((icn + i) * 3 + kk) * 256 + o0 + o4];
      }
    }
    // compute from LDS (chain identical to r7-r10)
    for (int i = 0; i < 16; i++) {
      float xq[4][6];
#pragma unroll
      for (int q = 0; q < 4; q++) {
        *(float4*)&xq[q][0] = *(const float4*)&ins[i][(q << 6) + (tx << 2)];
        *(float2*)&xq[q][4] = *(const float2*)&ins[i][(q << 6) + (tx << 2) + 4];
      }
      float wv[3][4], wb[3][4];
#pragma unroll
      for (int kk = 0; kk < 3; kk++) {
        const float* wrow = &wsl[((kk << 4) + i) << 7];
        *(float4*)wv[kk] = *(const float4*)&wrow[oy << 2];
        *(float4*)wb[kk] = *(const float4*)&wrow[64 + (oy << 2)];
      }
#pragma unroll
      for (int m = 0; m < 4; m++)
#pragma unroll
        for (int q = 0; q < 4; q++)
#pragma unroll
          for (int n = 0; n < 4; n++) {
            acc[0][m][(q << 2) + n] += wv[0][m] * xq[q][n] + wv[1][m] * xq[q][n + 1] + wv[2][m] * xq[q][n + 2];
            acc[1][m][(q << 2) + n] += wb[0][m] * xq[q][n] + wb[1][m] * xq[q][n + 1] + wb[2][m] * xq[q][n + 2];
          }
    }
  }
  float sh1[2] = {0.f, 0.f}, sh2[2] = {0.f, 0.f};
#pragma unroll
  for (int h = 0; h < 2; h++)
#pragma unroll
    for (int m = 0; m < 4; m++) {
      int o = o0 + (h << 6) + (oy << 2) + m;
      float bv = bias[o];
      size_t rowbase = (((size_t)((b << 8) + o)) << 11) + t0 + (tx << 2);
#pragma unroll
      for (int q = 0; q < 4; q++) {
        size_t row = rowbase + (q << 6);
#pragma unroll
        for (int n = 0; n < 4; n++) {
          float v = acc[h][m][(q << 2) + n] + bv;
          if (src) v += src[row + n];
          out[row + n] = v;
          sh1[h] += v; sh2[h] += v * v;
        }
      }
    }
  // stats epilogue: group = (y<<2) + (h<<1) + (oy>>3)
  __syncthreads();
  float* red = (float*)ins;
#pragma unroll
  for (int h = 0; h < 2; h++) {
    red[TID] = sh1[h]; red[256 + TID] = sh2[h];
    __syncthreads();
    for (int st = 64; st > 0; st >>= 1) {
      if ((TID & 127) < st) { red[TID] += red[TID + st]; red[256 + TID] += red[256 + TID + st]; }
      __syncthreads();
    }
    if ((TID & 127) == 0) {
      int g = (blockIdx.y << 2) + (h << 1) + (TID >> 7);
      atomicAdd(&partOut[(((b << 3) + g) << 1)], red[TID]);
      atomicAdd(&partOut[(((b << 3) + g) << 1) + 1], red[256 + TID]);
    }
    __syncthreads();
  }
}

// down conv k=8 stride 4, Tout=512. grid=(NB*8,4)
__global__ __launch_bounds__(256) void conv_down_k(const float* __restrict__ in, const float* __restrict__ wT,
                                                   const float* __restrict__ bias, float* __restrict__ out) {
  int b = blockIdx.x >> 3;
  int to0 = (blockIdx.x & 7) << 6;
  int o0 = blockIdx.y << 6;
  int tx = TID & 15, oy = TID >> 4;
  __shared__ float ins[16][264];
  __shared__ float wsl[16 * 512];
  float acc[4][4];
#pragma unroll
  for (int m = 0; m < 4; m++)
#pragma unroll
    for (int n = 0; n < 4; n++) acc[m][n] = 0.f;
  for (int ic0 = 0; ic0 < 256; ic0 += 16) {
    __syncthreads();
    for (int idx = TID; idx < 16 * 260; idx += 256) {
      int r = idx / 260, c = idx % 260;
      int s = (to0 << 2) - 2 + c;
      float v = 0.f;
      if (s >= 0 && s < 2048) v = in[(((size_t)((b << 8) + ic0 + r)) << 11) + s];
      ins[r][c] = v;
    }
    for (int idx = TID; idx < 16 * 512; idx += 256) {
      int o = idx & 63;
      int kk = (idx >> 6) & 7;
      int i = idx >> 9;
      wsl[idx] = wT[((ic0 + i) * 8 + kk) * 256 + o0 + o];
    }
    __syncthreads();
#pragma unroll 2
    for (int i = 0; i < 16; i++) {
      float xv[20];
#pragma unroll
      for (int q = 0; q < 5; q++) *(float4*)&xv[q * 4] = *(const float4*)&ins[i][(tx << 4) + (q << 2)];
      float wv[8][4];
#pragma unroll
      for (int kk = 0; kk < 8; kk++) *(float4*)wv[kk] = *(const float4*)&wsl[(i << 9) + (kk << 6) + (oy << 2)];
#pragma unroll
      for (int n = 0; n < 4; n++)
#pragma unroll
        for (int kk = 0; kk < 8; kk++) {
          float xval = xv[(n << 2) + kk];
#pragma unroll
          for (int m = 0; m < 4; m++) acc[m][n] += wv[kk][m] * xval;
        }
    }
  }
  int obase = o0 + (oy << 2);
#pragma unroll
  for (int m = 0; m < 4; m++) {
    int o = obase + m;
    float bv = bias[o];
    size_t rowo = (((size_t)((b << 8) + o)) << 9) + to0 + (tx << 2);
#pragma unroll
    for (int n = 0; n < 4; n++) out[rowo + n] = acc[m][n] + bv;
  }
}

// 1x1 conv, T=512. grid=(NB*8, O/64)
__global__ __launch_bounds__(256) void conv1x1_k(const float* __restrict__ in, const float* __restrict__ wIO,
                                                 const float* __restrict__ bias, float* __restrict__ out,
                                                 int Kc, int O) {
  int b = blockIdx.x >> 3;
  int t0 = (blockIdx.x & 7) << 6;
  int o0 = blockIdx.y << 6;
  int tx = TID & 15, oy = TID >> 4;
  __shared__ float xs[32][64];
  __shared__ float wsd[32][64];
  float acc[4][4];
#pragma unroll
  for (int m = 0; m < 4; m++)
#pragma unroll
    for (int n = 0; n < 4; n++) acc[m][n] = 0.f;
  for (int ic0 = 0; ic0 < Kc; ic0 += 32) {
    __syncthreads();
    for (int idx = TID; idx < 2048; idx += 256) {
      int r = idx >> 6, c = idx & 63;
      xs[r][c] = in[((size_t)(b * Kc + ic0 + r) << 9) + t0 + c];
      wsd[r][c] = wIO[(ic0 + r) * O + o0 + c];
    }
    __syncthreads();
#pragma unroll 8
    for (int i = 0; i < 32; i++) {
      float4 xvv = *(const float4*)&xs[i][tx << 2];
      float4 wvv = *(const float4*)&wsd[i][oy << 2];
      float xv[4] = {xvv.x, xvv.y, xvv.z, xvv.w};
      float wv[4] = {wvv.x, wvv.y, wvv.z, wvv.w};
#pragma unroll
      for (int m = 0; m < 4; m++)
#pragma unroll
        for (int n = 0; n < 4; n++) acc[m][n] += wv[m] * xv[n];
    }
  }
#pragma unroll
  for (int m = 0; m < 4; m++) {
    int o = o0 + (oy << 2) + m;
    float bv = bias[o];
    size_t rowo = ((size_t)(b * O + o) << 9) + t0 + (tx << 2);
#pragma unroll
    for (int n = 0; n < 4; n++) out[rowo + n] = acc[m][n] + bv;
  }
}

// ===== VQ tiled: BYTE-IDENTICAL to r7-passing kernel — do not touch =====
__global__ __launch_bounds__(256) void vq_tiled(const float* __restrict__ zE,
                                                const float* __restrict__ cb,
                                                const float* __restrict__ csq,
                                                int* __restrict__ codes) {
  int b = blockIdx.x >> 3;
  int t0 = (blockIdx.x & 7) << 6;
  int cq = TID & 15, pq = TID >> 4;
  __shared__ float Zs[128][66];
  __shared__ float Cs[64][129];
  __shared__ float zsqs[64];
  __shared__ float bd[64][17];
  __shared__ int bix[64][17];
  for (int idx = TID; idx < 128 * 64; idx += 256) {
    int c = idx >> 6, p = idx & 63;
    Zs[c][p] = zE[((size_t)(b * 128 + c) << 9) + t0 + p];
  }
  __syncthreads();
  if (TID < 64) {
    float s = 0.f;
    for (int c = 0; c < 128; c++) { float v = Zs[c][TID]; s += v * v; }
    zsqs[TID] = s;
  }
  float best[4];
  int bidx[4];
#pragma unroll
  for (int n = 0; n < 4; n++) { best[n] = 3.4e38f; bidx[n] = 0; }
  const int j0 = cq << 2;
  for (int cg = 0; cg < 16; cg++) {
    __syncthreads();
    for (int idx = TID; idx < 64 * 128; idx += 256) {
      int j = idx >> 7, c = idx & 127;
      Cs[j][c] = cb[((cg << 6) + j) * 128 + c];
    }
    __syncthreads();
    float acc[4][4];
#pragma unroll
    for (int u = 0; u < 4; u++)
#pragma unroll
      for (int n = 0; n < 4; n++) acc[u][n] = 0.f;
    for (int c = 0; c < 128; c++) {
      float4 zv4 = *(const float4*)&Zs[c][pq << 2];
      float zv[4] = {zv4.x, zv4.y, zv4.z, zv4.w};
      float cv[4];
#pragma unroll
      for (int u = 0; u < 4; u++) cv[u] = Cs[j0 + u][c];
#pragma unroll
      for (int u = 0; u < 4; u++)
#pragma unroll
        for (int n = 0; n < 4; n++) acc[u][n] += zv[n] * cv[u];
    }
#pragma unroll
    for (int u = 0; u < 4; u++) {
      int code = (cg << 6) + j0 + u;
      float cs_ = csq[code];
#pragma unroll
      for (int n = 0; n < 4; n++) {
        float A = zsqs[(pq << 2) + n] + cs_;
        float B = 2.0f * acc[u][n];
        float d = A - B;
        if (d < best[n]) { best[n] = d; bidx[n] = code; }
      }
    }
  }
  __syncthreads();
#pragma unroll
  for (int n = 0; n < 4; n++) { bd[(pq << 2) + n][cq] = best[n]; bix[(pq << 2) + n][cq] = bidx[n]; }
  __syncthreads();
  if (TID < 64) {
    float bb = bd[TID][0];
    int bj = bix[TID][0];
    for (int q = 1; q < 16; q++) {
      float d = bd[TID][q];
      int j = bix[TID][q];
      if (d < bb || (d == bb && j < bj)) { bb = d; bj = j; }
    }
    codes[(b << 9) + t0 + TID] = bj;
  }
}

// ================= VQ bookkeeping =================
__global__ void count_k(const int* __restrict__ codes, float* __restrict__ counts) {
  int n = blockIdx.x * blockDim.x + TID;
  if (n < 16384) atomicAdd(&counts[codes[n]], 1.f);
}

__global__ __launch_bounds__(256) void gather_k(const float* __restrict__ cb, const int* __restrict__ codes,
                                                const float* __restrict__ zE, float* __restrict__ zQ,
                                                float* __restrict__ vqsum) {
  double part = 0.;
  const int total = 32 * 128 * 512;
  for (int idx = blockIdx.x * blockDim.x + TID; idx < total; idx += gridDim.x * blockDim.x) {
    int t = idx & 511;
    int c = (idx >> 9) & 127;
    int b = idx >> 16;
    int code = codes[(b << 9) + t];
    float q = cb[code * 128 + c];
    double d = (double)q - (double)zE[idx];
    zQ[idx] = q;
    part += d * d;
  }
  __shared__ double red[256];
  red[TID] = part;
  __syncthreads();
  for (int st = 128; st > 0; st >>= 1) {
    if (TID < st) red[TID] += red[TID + st];
    __syncthreads();
  }
  if (TID == 0) atomicAdd(vqsum, (float)red[0]);
}

// ================= decoder-only convs =================
// transposed conv up, with GN-stats epilogue. grid=(NB*17,4)
__global__ __launch_bounds__(256) void conv_up_k(const float* __restrict__ in, const float* __restrict__ w,
                                                 const float* __restrict__ bias, float* __restrict__ out,
                                                 float* __restrict__ partOut) {
  int b = blockIdx.x / 17;
  int s0 = (blockIdx.x % 17) << 5;
  int o0 = blockIdx.y << 6;
  int tx = TID & 15, oy = TID >> 4;
  __shared__ float ins[16][36];
  __shared__ float wsl[16 * 512];
  float acc[2][4][4];
#pragma unroll
  for (int j = 0; j < 2; j++)
#pragma unroll
    for (int m = 0; m < 4; m++)
#pragma unroll
      for (int r = 0; r < 4; r++) acc[j][m][r] = 0.f;
  for (int ic0 = 0; ic0 < 256; ic0 += 16) {
    __syncthreads();
    for (int idx = TID; idx < 16 * 34; idx += 256) {
      int r = idx / 34, c = idx % 34;
      int s = s0 - 1 + c;
      float v = 0.f;
      if (s >= 0 && s < 512) v = in[(((size_t)((b << 8) + ic0 + r)) << 9) + s];
      ins[r][c] = v;
    }
    for (int idx = TID; idx < 8192; idx += 256) {
      int rr = idx & 3;
      int o = (idx >> 2) & 63;
      int h = (idx >> 8) & 1;
      int i = idx >> 9;
      wsl[idx] = w[(((size_t)(ic0 + i)) << 11) + ((size_t)(o0 + o) << 3) + (h << 2) + rr];
    }
    __syncthreads();
#pragma unroll 2
    for (int i = 0; i < 16; i++) {
      float x0 = ins[i][2 * tx], x1 = ins[i][2 * tx + 1], x2 = ins[i][2 * tx + 2];
#pragma unroll
      for (int m = 0; m < 4; m++) {
        int om = (oy << 2) + m;
        float4 wa4 = *(const float4*)&wsl[(i << 9) + (om << 2)];
        float4 wb4 = *(const float4*)&wsl[(i << 9) + 256 + (om << 2)];
        float wa[4] = {wa4.x, wa4.y, wa4.z, wa4.w};
        float wb[4] = {wb4.x, wb4.y, wb4.z, wb4.w};
#pragma unroll
        for (int r = 0; r < 4; r++) {
          acc[0][m][r] += x1 * wa[r] + x0 * wb[r];
          acc[1][m][r] += x2 * wa[r] + x1 * wb[r];
        }
      }
    }
  }
  float s1 = 0.f, s2 = 0.f;
#pragma unroll
  for (int j = 0; j < 2; j++) {
    int sS = s0 + (tx << 1) + j;
#pragma unroll
    for (int m = 0; m < 4; m++) {
      int o = o0 + (oy << 2) + m;
      float bv = bias[o];
#pragma unroll
      for (int r = 0; r < 4; r++) {
        int t = (sS << 2) + r - 2;
        if (t >= 0 && t < 2048) {
          float v = acc[j][m][r] + bv;
          out[(((size_t)((b << 8) + o)) << 11) + t] = v;
          s1 += v; s2 += v * v;
        }
      }
    }
  }
  // stats epilogue: group = (y<<1) | (oy>>3)
  __syncthreads();
  float* red = (float*)ins;  // 576 floats available >= 512
  red[TID] = s1; red[256 + TID] = s2;
  __syncthreads();
  for (int st = 64; st > 0; st >>= 1) {
    if ((TID & 127) < st) { red[TID] += red[TID + st]; red[256 + TID] += red[256 + TID + st]; }
    __syncthreads();
  }
  if ((TID & 127) == 0) {
    int g = (blockIdx.y << 1) + (TID >> 7);
    atomicAdd(&partOut[(((b << 3) + g) << 1)], red[TID]);
    atomicAdd(&partOut[(((b << 3) + g) << 1) + 1], red[256 + TID]);
  }
}

__global__ __launch_bounds__(256) void conv_out_k(const float* __restrict__ in, const float* __restrict__ wP,
                                                  const float* __restrict__ bias, float* __restrict__ xhat) {
  int b = blockIdx.x >> 5;
  int t0 = (blockIdx.x & 31) << 6;
  int tx = TID & 63, oy = TID >> 6;
  __shared__ float ins[32][68];
  __shared__ float wsl[32 * 144];
  float acc[9];
#pragma unroll
  for (int m = 0; m < 9; m++) acc[m] = 0.f;
  for (int ic0 = 0; ic0 < 256; ic0 += 32) {
    __syncthreads();
    for (int idx = TID; idx < 32 * 66; idx += 256) {
      int r = idx / 66, c = idx % 66;
      int t = t0 - 1 + c;
      float v = 0.f;
      if (t >= 0 && t < 2048) v = in[(((size_t)((b << 8) + ic0 + r)) << 11) + t];
      ins[r][c] = v;
    }
    for (int idx = TID; idx < 32 * 144; idx += 256) {
      wsl[idx] = wP[ic0 * 144 + idx];
    }
    __syncthreads();
#pragma unroll 4
    for (int i = 0; i < 32; i++) {
      float x0 = ins[i][tx], x1 = ins[i][tx + 1], x2 = ins[i][tx + 2];
#pragma unroll
      for (int m = 0; m < 9; m++) {
        int o = oy * 9 + m;
        float4 wv = *(const float4*)&wsl[(i * 36 + o) << 2];
        acc[m] += wv.x * x0 + wv.y * x1 + wv.z * x2;
      }
    }
  }
  size_t orow = ((size_t)(b << 11) + t0 + tx) * 36;
#pragma unroll
  for (int m = 0; m < 9; m++) {
    int o = oy * 9 + m;
    xhat[orow + o] = acc[m] + bias[o];
  }
}

// ================= losses =================
__global__ __launch_bounds__(256) void loss_k(const float* __restrict__ x, const float* __restrict__ xh,
                                              const float* __restrict__ mask, float* __restrict__ scal) {
  float pos = 0.f, dir = 0.f, ms = 0.f;
  for (int n = blockIdx.x * blockDim.x + TID; n < 65536; n += gridDim.x * blockDim.x) {
    const float* xp = x + (size_t)n * 36;
    const float* hp = xh + (size_t)n * 36;
    float a[36], h[36];
#pragma unroll
    for (int d4 = 0; d4 < 36; d4 += 4) {
      *(float4*)&a[d4] = *(const float4*)&xp[d4];
      *(float4*)&h[d4] = *(const float4*)&hp[d4];
    }
#pragma unroll
    for (int d = 0; d < 36; d++) {
      if (d < 21 || (d >= 27 && d < 30)) {
        float df = h[d] - a[d];
        float ad = fabsf(df);
        pos += (ad < 1.f) ? 0.5f * df * df : ad - 0.5f;
      }
    }
    float mL = mask[2 * (size_t)n], mR = mask[2 * (size_t)n + 1];
    const int vb[4] = {21, 24, 30, 33};
    float mv[4] = {mL, mL, mR, mR};
#pragma unroll
    for (int v = 0; v < 4; v++) {
      int o = vb[v];
      float ax = a[o], ay = a[o + 1], az = a[o + 2];
      float hx = h[o], hy = h[o + 1], hz = h[o + 2];
      float an = sqrtf(ax * ax + ay * ay + az * az) + 1e-8f;
      float hn = sqrtf(hx * hx + hy * hy + hz * hz) + 1e-8f;
      float cs = (ax * hx + ay * hy + az * hz) / (an * hn);
      dir += (1.f - cs) * mv[v];
    }
    ms += 2.f * (mL + mR);
  }
  __shared__ float rp[256], rd[256], rm[256];
  rp[TID] = pos; rd[TID] = dir; rm[TID] = ms;
  __syncthreads();
  for (int st = 128; st > 0; st >>= 1) {
    if (TID < st) { rp[TID] += rp[TID + st]; rd[TID] += rd[TID + st]; rm[TID] += rm[TID + st]; }
    __syncthreads();
  }
  if (TID == 0) {
    atomicAdd(&scal[1], rp[0]);
    atomicAdd(&scal[2], rd[0]);
    atomicAdd(&scal[3], rm[0]);
  }
}

__global__ __launch_bounds__(256) void finalize_k(const float* __restrict__ counts, const float* __restrict__ scal,
                                                  float* __restrict__ tail) {
  __shared__ float red[256];
  float s = 0.f;
  for (int j = TID; j < 1024; j += 256) {
    float avg = counts[j] * (1.f / 16384.f);
    s += avg * logf(avg + 1e-10f);
  }
  red[TID] = s;
  __syncthreads();
  for (int st = 128; st > 0; st >>= 1) {
    if (TID < st) red[TID] += red[TID + st];
    __syncthreads();
  }
  if (TID == 0) {
    tail[0] = 1.25f * scal[0] * (1.f / 2097152.f);
    tail[1] = expf(-red[0]);
    tail[2] = scal[1] * (1.f / 65536.f);
    tail[3] = scal[2] / fmaxf(scal[3], 1.f);
  }
}

__global__ void codesf_k(const int* __restrict__ codes, float* __restrict__ o) {
  int n = blockIdx.x * blockDim.x + TID;
  if (n < 16384) o[n] = (float)codes[n];
}

// ================= host =================
extern "C" void kernel_launch(void* const* d_in, const int* in_sizes, int n_in,
                              void* d_out, int out_size, void* d_ws, size_t ws_size,
                              hipStream_t stream) {
  const float* x = (const float*)d_in[0];
  const float* mask = (const float*)d_in[1];
  const float* enc_in_w = (const float*)d_in[2];
  const float* enc_in_b = (const float*)d_in[3];
  const float* enc_gn1_g = (const float*)d_in[4];
  const float* enc_gn1_b = (const float*)d_in[5];
  const float* enc_c1_w = (const float*)d_in[6];
  const float* enc_c1_b = (const float*)d_in[7];
  const float* enc_gn2_g = (const float*)d_in[8];
  const float* enc_gn2_b = (const float*)d_in[9];
  const float* enc_c2_w = (const float*)d_in[10];
  const float* enc_c2_b = (const float*)d_in[11];
  const float* down_w = (const float*)d_in[12];
  const float* down_b = (const float*)d_in[13];
  const float* enc_out_w = (const float*)d_in[14];
  const float* enc_out_b = (const float*)d_in[15];
  const float* codebook = (const float*)d_in[16];
  const float* dec_in_w = (const float*)d_in[17];
  const float* dec_in_b = (const float*)d_in[18];
  const float* up_w = (const float*)d_in[19];
  const float* up_b = (const float*)d_in[20];
  const float* dec_gn1_g = (const float*)d_in[21];
  const float* dec_gn1_b = (const float*)d_in[22];
  const float* dec_c1_w = (const float*)d_in[23];
  const float* dec_c1_b = (const float*)d_in[24];
  const float* dec_gn2_g = (const float*)d_in[25];
  const float* dec_gn2_b = (const float*)d_in[26];
  const float* dec_c2_w = (const float*)d_in[27];
  const float* dec_c2_b = (const float*)d_in[28];
  const float* dec_out_w = (const float*)d_in[29];
  const float* dec_out_b = (const float*)d_in[30];

  char* W = (char*)d_ws;
  float* zE = (float*)(W + 0);                        // 8,388,608
  float* zQ = (float*)(W + 8388608);                  // 8,388,608
  int* codes = (int*)(W + 16777216);                  // 65,536
  float* counts = (float*)(W + 16842752);             // 4,096 (1024 f)
  float* scal = (float*)(W + 16846848);               // 32 (8 f, contiguous after counts)
  float* stats = (float*)(W + 16846880);              // 18 slots x 512 f = 36,864 B (contiguous after scal)
  float* csq = (float*)(W + 16883744);                // 4,096
  float* wf_enc_in = (float*)(W + 16887840);          // 110,592
  float* wf_enc_c1 = (float*)(W + 16998432);          // 3,145,728
  float* wf_enc_c2 = (float*)(W + 20144160);          // 3,145,728
  float* wf_down = (float*)(W + 23289888);            // 2,097,152
  float* wf_enc_out = (float*)(W + 25387040);         // 131,072
  float* wf_dec_in = (float*)(W + 25518112);          // 131,072
  float* wf_dec_c1 = (float*)(W + 25649184);          // 3,145,728
  float* wf_dec_c2 = (float*)(W + 28794912);          // 3,145,728
  float* wf_dec_out = (float*)(W + 31940640);         // 147,456
  // big region @48MiB: f0, f2 (67.1MB each, 32 batches) + dech (16.8MB)
  float* f0 = (float*)(W + 50331648);
  float* f2 = (float*)(W + 50331648 + (size_t)67108864);
  float* dech = (float*)(W + 50331648 + 2 * (size_t)67108864);

  dim3 blk(256);
  // zero counts (1024) + scal (8) + stats (18*512=9216) — contiguous
  zero_k<<<dim3(41), blk, 0, stream>>>(counts, 1024 + 8 + 9216);
  perm_oik_iko<<<dim3(128), blk, 0, stream>>>(enc_in_w, wf_enc_in, 1, 256, 36, 3);
  perm_oik_iko<<<dim3(1024), blk, 0, stream>>>(enc_c1_w, wf_enc_c1, 4, 256, 256, 3);
  perm_oik_iko<<<dim3(1024), blk, 0, stream>>>(enc_c2_w, wf_enc_c2, 4, 256, 256, 3);
  perm_oik_iko<<<dim3(1024), blk, 0, stream>>>(down_w, wf_down, 1, 256, 256, 8);
  perm_oik_iko<<<dim3(128), blk, 0, stream>>>(enc_out_w, wf_enc_out, 1, 128, 256, 1);
  perm_oik_iko<<<dim3(128), blk, 0, stream>>>(dec_in_w, wf_dec_in, 1, 256, 128, 1);
  perm_oik_iko<<<dim3(1024), blk, 0, stream>>>(dec_c1_w, wf_dec_c1, 4, 256, 256, 3);
  perm_oik_iko<<<dim3(1024), blk, 0, stream>>>(dec_c2_w, wf_dec_c2, 4, 256, 256, 3);
  perm_decout<<<dim3(64), blk, 0, stream>>>(dec_out_w, wf_dec_out);
  csq_f32<<<dim3(4), blk, 0, stream>>>(codebook, csq);

  // ---- encoder (fp32), whole batch; stats slots 0..8 ----
  conv_in_k<<<dim3(NB * 32, 4), blk, 0, stream>>>(x, wf_enc_in, enc_in_b, f0, stats + 0 * 512);
  for (int i = 0; i < 4; i++) {
    float* sIn = stats + (2 * i) * 512;
    float* sMid = stats + (2 * i + 1) * 512;
    float* sOut = stats + (2 * i + 2) * 512;
    conv3_gn_k<<<dim3(NB * 8, 2), blk, 0, stream>>>(f0, sIn, enc_gn1_g + i * 256, enc_gn1_b + i * 256,
                                                    wf_enc_c1 + i * 196608, enc_c1_b + i * 256, nullptr, f2, sMid);
    conv3_gn_k<<<dim3(NB * 8, 2), blk, 0, stream>>>(f2, sMid, enc_gn2_g + i * 256, enc_gn2_b + i * 256,
                                                    wf_enc_c2 + i * 196608, enc_c2_b + i * 256, f0, f0, sOut);
  }
  conv_down_k<<<dim3(NB * 8, 4), blk, 0, stream>>>(f0, wf_down, down_b, f2);
  conv1x1_k<<<dim3(NB * 8, 2), blk, 0, stream>>>(f2, wf_enc_out, enc_out_b, zE, 256, 128);

  // ---- quantize ----
  vq_tiled<<<dim3(256), blk, 0, stream>>>(zE, codebook, csq, codes);
  count_k<<<dim3(64), blk, 0, stream>>>(codes, counts);
  gather_k<<<dim3(512), blk, 0, stream>>>(codebook, codes, zE, zQ, &scal[0]);

  // ---- decoder (fp32), whole batch; stats slots 9..17 ----
  float* xhat = (float*)d_out;
  conv1x1_k<<<dim3(NB * 8, 4), blk, 0, stream>>>(zQ, wf_dec_in, dec_in_b, dech, 128, 256);
  conv_up_k<<<dim3(NB * 17, 4), blk, 0, stream>>>(dech, up_w, up_b, f0, stats + 9 * 512);
  for (int i = 0; i < 4; i++) {
    float* sIn = stats + (9 + 2 * i) * 512;
    float* sMid = stats + (10 + 2 * i) * 512;
    float* sOut = stats + (11 + 2 * i) * 512;
    conv3_gn_k<<<dim3(NB * 8, 2), blk, 0, stream>>>(f0, sIn, dec_gn1_g + i * 256, dec_gn1_b + i * 256,
                                                    wf_dec_c1 + i * 196608, dec_c1_b + i * 256, nullptr, f2, sMid);
    conv3_gn_k<<<dim3(NB * 8, 2), blk, 0, stream>>>(f2, sMid, dec_gn2_g + i * 256, dec_gn2_b + i * 256,
                                                    wf_dec_c2 + i * 196608, dec_c2_b + i * 256, f0, f0, sOut);
  }
  conv_out_k<<<dim3(NB * 32), blk, 0, stream>>>(f0, wf_dec_out, dec_out_b, xhat);

  // ---- losses / scalars ----
  loss_k<<<dim3(256), blk, 0, stream>>>(x, xhat, mask, scal);
  finalize_k<<<dim3(1), blk, 0, stream>>>(counts, scal, (float*)d_out + 2375680);
  codesf_k<<<dim3(64), blk, 0, stream>>>(codes, (float*)d_out + 2359296);
}

// Round 12
// 6664.002 us; speedup vs baseline: 1.2094x; 1.1986x over previous
//
#include <hip/hip_runtime.h>
#include <cstddef>
#include <cstdint>

// VQ-VAE 1D forward — full fp32 pipeline.
// Codes: reference argmin follows fp32 dist = fl(zsq+csq) - fl(2*zc), first-index ties.
// vq_tiled is BYTE-IDENTICAL to the r7-passing kernel (the only tie-sensitive chain).
// z_e tolerates ~1e-6 perturbation (r0/r3/r11 evidence), so conv rounding may change.
// R12: conv3_gn — prefetch reverted (r11 net-negative), inner loop as explicit fmaf
// chains (3 FMA/triple vs mul+2fma+add), stats epilogue skipped when unused.
// d_out: x_hat (B,T,36) | codes as float (B,512) | [loss_vq, perplexity, loss_pos, loss_dir]

#define TID ((int)threadIdx.x)
#define NB 32  // whole batch, single pass

__device__ __forceinline__ float silu_f(float y) { return y / (1.f + expf(-y)); }

// ================= weight prep =================
__global__ void perm_oik_iko(const float* __restrict__ src, float* __restrict__ dst,
                             int R, int O, int I, int K) {
  int n = R * O * I * K;
  for (int idx = blockIdx.x * blockDim.x + TID; idx < n; idx += gridDim.x * blockDim.x) {
    int o = idx % O;
    int k = (idx / O) % K;
    int i = (idx / (O * K)) % I;
    int r = idx / (O * K * I);
    dst[idx] = src[((r * O + o) * I + i) * K + k];
  }
}

__global__ void perm_decout(const float* __restrict__ src, float* __restrict__ dst) {
  int n = 256 * 36 * 4;
  for (int idx = blockIdx.x * blockDim.x + TID; idx < n; idx += gridDim.x * blockDim.x) {
    int k = idx & 3;
    int o = (idx >> 2) % 36;
    int i = idx / 144;
    dst[idx] = (k < 3) ? src[(o * 256 + i) * 3 + k] : 0.f;
  }
}

__global__ void zero_k(float* p, int n) {
  int i = blockIdx.x * blockDim.x + TID;
  if (i < n) p[i] = 0.f;
}

// csq[j] = fp32 sequential sum of fl(c*c)
__global__ void csq_f32(const float* __restrict__ cb, float* __restrict__ csq) {
  int j = blockIdx.x * blockDim.x + TID;
  if (j < 1024) {
    float s = 0.f;
    for (int c = 0; c < 128; c++) { float v = cb[j * 128 + c]; s += v * v; }
    csq[j] = s;
  }
}

// ================= fp32 convs =================
// input conv 36->256, k=3, with GN-stats epilogue. grid=(NB*32,4)
__global__ __launch_bounds__(256) void conv_in_k(const float* __restrict__ x, const float* __restrict__ wT,
                                                 const float* __restrict__ bias, float* __restrict__ out,
                                                 float* __restrict__ partOut) {
  int b = blockIdx.x >> 5;
  int t0 = (blockIdx.x & 31) << 6;
  int o0 = blockIdx.y << 6;
  int tx = TID & 15, oy = TID >> 4;
  __shared__ float ins[36][68];
  __shared__ float wsl[36 * 192];
  for (int idx = TID; idx < 36 * 66; idx += 256) {
    int i = idx % 36, c = idx / 36;
    int t = t0 - 1 + c;
    float v = 0.f;
    if (t >= 0 && t < 2048) v = x[((size_t)(b * 2048 + t)) * 36 + i];
    ins[i][c] = v;
  }
  for (int idx = TID; idx < 36 * 192; idx += 256) {
    int o = idx & 63;
    int kk = (idx >> 6) % 3;
    int i = idx / 192;
    wsl[idx] = wT[(i * 3 + kk) * 256 + o0 + o];
  }
  __syncthreads();
  float acc[4][4];
#pragma unroll
  for (int m = 0; m < 4; m++)
#pragma unroll
    for (int n = 0; n < 4; n++) acc[m][n] = 0.f;
  for (int i = 0; i < 36; i++) {
    float xv[6];
    float4 x4 = *(const float4*)&ins[i][tx << 2];
    xv[0] = x4.x; xv[1] = x4.y; xv[2] = x4.z; xv[3] = x4.w;
    xv[4] = ins[i][(tx << 2) + 4];
    xv[5] = ins[i][(tx << 2) + 5];
    const float* wrow = &wsl[i * 192];
    float wv[3][4];
    *(float4*)wv[0] = *(const float4*)&wrow[oy << 2];
    *(float4*)wv[1] = *(const float4*)&wrow[64 + (oy << 2)];
    *(float4*)wv[2] = *(const float4*)&wrow[128 + (oy << 2)];
#pragma unroll
    for (int m = 0; m < 4; m++)
#pragma unroll
      for (int n = 0; n < 4; n++)
        acc[m][n] = fmaf(wv[0][m], xv[n], fmaf(wv[1][m], xv[n + 1], fmaf(wv[2][m], xv[n + 2], acc[m][n])));
  }
  int obase = o0 + (oy << 2);
  float s1 = 0.f, s2 = 0.f;
#pragma unroll
  for (int m = 0; m < 4; m++) {
    int o = obase + m;
    float bv = bias[o];
    size_t rowo = (((size_t)((b << 8) + o)) << 11) + t0 + (tx << 2);
#pragma unroll
    for (int n = 0; n < 4; n++) {
      float v = acc[m][n] + bv;
      out[rowo + n] = v;
      s1 += v; s2 += v * v;
    }
  }
  __syncthreads();
  float* red = (float*)ins;
  red[TID] = s1; red[256 + TID] = s2;
  __syncthreads();
  for (int st = 64; st > 0; st >>= 1) {
    if ((TID & 127) < st) { red[TID] += red[TID + st]; red[256 + TID] += red[256 + TID + st]; }
    __syncthreads();
  }
  if ((TID & 127) == 0) {
    int g = (blockIdx.y << 1) + (TID >> 7);
    atomicAdd(&partOut[(((b << 3) + g) << 1)], red[TID]);
    atomicAdd(&partOut[(((b << 3) + g) << 1) + 1], red[256 + TID]);
  }
}

// k=3 conv 256->256 with fused GN+SiLU input (stats from partIn) + optional stats epilogue.
// o-tile 128, t-tile 256, ic-chunk 16, direct staging, fmaf-chained inner loop.
// grid=(NB*8, 2).
__global__ __launch_bounds__(256, 2) void conv3_gn_k(const float* __restrict__ in, const float* __restrict__ partIn,
                                                     const float* __restrict__ gamma, const float* __restrict__ beta,
                                                     const float* __restrict__ wT, const float* __restrict__ bias,
                                                     const float* __restrict__ src, float* __restrict__ out,
                                                     float* __restrict__ partOut) {
  int b = blockIdx.x >> 3;
  int t0 = (blockIdx.x & 7) << 8;
  int o0 = blockIdx.y << 7;
  int tx = TID & 15, oy = TID >> 4;
  __shared__ float ins[16][264];     // 260 used
  __shared__ float wsl[3 * 16 * 128];
  float acc[2][4][16];
#pragma unroll
  for (int h = 0; h < 2; h++)
#pragma unroll
    for (int m = 0; m < 4; m++)
#pragma unroll
      for (int n = 0; n < 16; n++) acc[h][m][n] = 0.f;
  for (int ic0 = 0; ic0 < 256; ic0 += 16) {
    int g = ic0 >> 5;
    const float* pp = partIn + (((size_t)((b << 3) + g)) << 1);
    float s1 = pp[0], s2 = pp[1];
    float mu = s1 * (1.f / 65536.f);
    float var = s2 * (1.f / 65536.f) - mu * mu;
    float rs = rsqrtf(var + 1e-5f);
    __syncthreads();
    // stage x: row r = oy, 16 lanes per row, per-row GN constants hoisted
    {
      int ch = ic0 + oy;
      float a = rs * gamma[ch];
      float bb = beta[ch] - mu * a;
      const float* grow = in + (((size_t)((b << 8) + ch)) << 11);
#pragma unroll
      for (int q = 0; q < 17; q++) {
        int c = tx + (q << 4);
        if (c < 260) {
          int t = t0 - 1 + c;
          float v = 0.f;
          if (t >= 0 && t < 2048) {
            float h = grow[t];
            float y = h * a + bb;
            v = y / (1.f + expf(-y));
          }
          ins[oy][c] = v;
        }
      }
    }
    // stage w: layout wsl[(kk*16+i)*128 + o]
    for (int idx4 = TID; idx4 < 1536; idx4 += 256) {
      int o4 = (idx4 & 31) << 2;
      int i = (idx4 >> 5) & 15;
      int kk = idx4 >> 9;
      *(float4*)&wsl[(((kk << 4) + i) << 7) + o4] =
          *(const float4*)&wT[((ic0 + i) * 3 + kk) * 256 + o0 + o4];
    }
    __syncthreads();
    for (int i = 0; i < 16; i++) {
      float xq[4][6];
#pragma unroll
      for (int q = 0; q < 4; q++) {
        *(float4*)&xq[q][0] = *(const float4*)&ins[i][(q << 6) + (tx << 2)];
        *(float2*)&xq[q][4] = *(const float2*)&ins[i][(q << 6) + (tx << 2) + 4];
      }
      float wv[3][4], wb[3][4];
#pragma unroll
      for (int kk = 0; kk < 3; kk++) {
        const float* wrow = &wsl[((kk << 4) + i) << 7];
        *(float4*)wv[kk] = *(const float4*)&wrow[oy << 2];
        *(float4*)wb[kk] = *(const float4*)&wrow[64 + (oy << 2)];
      }
#pragma unroll
      for (int m = 0; m < 4; m++)
#pragma unroll
        for (int q = 0; q < 4; q++)
#pragma unroll
          for (int n = 0; n < 4; n++) {
            acc[0][m][(q << 2) + n] =
                fmaf(wv[0][m], xq[q][n], fmaf(wv[1][m], xq[q][n + 1], fmaf(wv[2][m], xq[q][n + 2], acc[0][m][(q << 2) + n])));
            acc[1][m][(q << 2) + n] =
                fmaf(wb[0][m], xq[q][n], fmaf(wb[1][m], xq[q][n + 1], fmaf(wb[2][m], xq[q][n + 2], acc[1][m][(q << 2) + n])));
          }
    }
  }
  float sh1[2] = {0.f, 0.f}, sh2[2] = {0.f, 0.f};
#pragma unroll
  for (int h = 0; h < 2; h++)
#pragma unroll
    for (int m = 0; m < 4; m++) {
      int o = o0 + (h << 6) + (oy << 2) + m;
      float bv = bias[o];
      size_t rowbase = (((size_t)((b << 8) + o)) << 11) + t0 + (tx << 2);
#pragma unroll
      for (int q = 0; q < 4; q++) {
        size_t row = rowbase + (q << 6);
#pragma unroll
        for (int n = 0; n < 4; n++) {
          float v = acc[h][m][(q << 2) + n] + bv;
          if (src) v += src[row + n];
          out[row + n] = v;
          sh1[h] += v; sh2[h] += v * v;
        }
      }
    }
  if (partOut) {
    __syncthreads();
    float* red = (float*)ins;
#pragma unroll
    for (int h = 0; h < 2; h++) {
      red[TID] = sh1[h]; red[256 + TID] = sh2[h];
      __syncthreads();
      for (int st = 64; st > 0; st >>= 1) {
        if ((TID & 127) < st) { red[TID] += red[TID + st]; red[256 + TID] += red[256 + TID + st]; }
        __syncthreads();
      }
      if ((TID & 127) == 0) {
        int g = (blockIdx.y << 2) + (h << 1) + (TID >> 7);
        atomicAdd(&partOut[(((b << 3) + g) << 1)], red[TID]);
        atomicAdd(&partOut[(((b << 3) + g) << 1) + 1], red[256 + TID]);
      }
      __syncthreads();
    }
  }
}

// down conv k=8 stride 4, Tout=512. grid=(NB*8,4)
__global__ __launch_bounds__(256) void conv_down_k(const float* __restrict__ in, const float* __restrict__ wT,
                                                   const float* __restrict__ bias, float* __restrict__ out) {
  int b = blockIdx.x >> 3;
  int to0 = (blockIdx.x & 7) << 6;
  int o0 = blockIdx.y << 6;
  int tx = TID & 15, oy = TID >> 4;
  __shared__ float ins[16][264];
  __shared__ float wsl[16 * 512];
  float acc[4][4];
#pragma unroll
  for (int m = 0; m < 4; m++)
#pragma unroll
    for (int n = 0; n < 4; n++) acc[m][n] = 0.f;
  for (int ic0 = 0; ic0 < 256; ic0 += 16) {
    __syncthreads();
    for (int idx = TID; idx < 16 * 260; idx += 256) {
      int r = idx / 260, c = idx % 260;
      int s = (to0 << 2) - 2 + c;
      float v = 0.f;
      if (s >= 0 && s < 2048) v = in[(((size_t)((b << 8) + ic0 + r)) << 11) + s];
      ins[r][c] = v;
    }
    for (int idx = TID; idx < 16 * 512; idx += 256) {
      int o = idx & 63;
      int kk = (idx >> 6) & 7;
      int i = idx >> 9;
      wsl[idx] = wT[((ic0 + i) * 8 + kk) * 256 + o0 + o];
    }
    __syncthreads();
#pragma unroll 2
    for (int i = 0; i < 16; i++) {
      float xv[20];
#pragma unroll
      for (int q = 0; q < 5; q++) *(float4*)&xv[q * 4] = *(const float4*)&ins[i][(tx << 4) + (q << 2)];
      float wv[8][4];
#pragma unroll
      for (int kk = 0; kk < 8; kk++) *(float4*)wv[kk] = *(const float4*)&wsl[(i << 9) + (kk << 6) + (oy << 2)];
#pragma unroll
      for (int n = 0; n < 4; n++)
#pragma unroll
        for (int kk = 0; kk < 8; kk++) {
          float xval = xv[(n << 2) + kk];
#pragma unroll
          for (int m = 0; m < 4; m++) acc[m][n] = fmaf(wv[kk][m], xval, acc[m][n]);
        }
    }
  }
  int obase = o0 + (oy << 2);
#pragma unroll
  for (int m = 0; m < 4; m++) {
    int o = obase + m;
    float bv = bias[o];
    size_t rowo = (((size_t)((b << 8) + o)) << 9) + to0 + (tx << 2);
#pragma unroll
    for (int n = 0; n < 4; n++) out[rowo + n] = acc[m][n] + bv;
  }
}

// 1x1 conv, T=512. grid=(NB*8, O/64)
__global__ __launch_bounds__(256) void conv1x1_k(const float* __restrict__ in, const float* __restrict__ wIO,
                                                 const float* __restrict__ bias, float* __restrict__ out,
                                                 int Kc, int O) {
  int b = blockIdx.x >> 3;
  int t0 = (blockIdx.x & 7) << 6;
  int o0 = blockIdx.y << 6;
  int tx = TID & 15, oy = TID >> 4;
  __shared__ float xs[32][64];
  __shared__ float wsd[32][64];
  float acc[4][4];
#pragma unroll
  for (int m = 0; m < 4; m++)
#pragma unroll
    for (int n = 0; n < 4; n++) acc[m][n] = 0.f;
  for (int ic0 = 0; ic0 < Kc; ic0 += 32) {
    __syncthreads();
    for (int idx = TID; idx < 2048; idx += 256) {
      int r = idx >> 6, c = idx & 63;
      xs[r][c] = in[((size_t)(b * Kc + ic0 + r) << 9) + t0 + c];
      wsd[r][c] = wIO[(ic0 + r) * O + o0 + c];
    }
    __syncthreads();
#pragma unroll 8
    for (int i = 0; i < 32; i++) {
      float4 xvv = *(const float4*)&xs[i][tx << 2];
      float4 wvv = *(const float4*)&wsd[i][oy << 2];
      float xv[4] = {xvv.x, xvv.y, xvv.z, xvv.w};
      float wv[4] = {wvv.x, wvv.y, wvv.z, wvv.w};
#pragma unroll
      for (int m = 0; m < 4; m++)
#pragma unroll
        for (int n = 0; n < 4; n++) acc[m][n] = fmaf(wv[m], xv[n], acc[m][n]);
    }
  }
#pragma unroll
  for (int m = 0; m < 4; m++) {
    int o = o0 + (oy << 2) + m;
    float bv = bias[o];
    size_t rowo = ((size_t)(b * O + o) << 9) + t0 + (tx << 2);
#pragma unroll
    for (int n = 0; n < 4; n++) out[rowo + n] = acc[m][n] + bv;
  }
}

// ===== VQ tiled: BYTE-IDENTICAL to r7-passing kernel — do not touch =====
__global__ __launch_bounds__(256) void vq_tiled(const float* __restrict__ zE,
                                                const float* __restrict__ cb,
                                                const float* __restrict__ csq,
                                                int* __restrict__ codes) {
  int b = blockIdx.x >> 3;
  int t0 = (blockIdx.x & 7) << 6;
  int cq = TID & 15, pq = TID >> 4;
  __shared__ float Zs[128][66];
  __shared__ float Cs[64][129];
  __shared__ float zsqs[64];
  __shared__ float bd[64][17];
  __shared__ int bix[64][17];
  for (int idx = TID; idx < 128 * 64; idx += 256) {
    int c = idx >> 6, p = idx & 63;
    Zs[c][p] = zE[((size_t)(b * 128 + c) << 9) + t0 + p];
  }
  __syncthreads();
  if (TID < 64) {
    float s = 0.f;
    for (int c = 0; c < 128; c++) { float v = Zs[c][TID]; s += v * v; }
    zsqs[TID] = s;
  }
  float best[4];
  int bidx[4];
#pragma unroll
  for (int n = 0; n < 4; n++) { best[n] = 3.4e38f; bidx[n] = 0; }
  const int j0 = cq << 2;
  for (int cg = 0; cg < 16; cg++) {
    __syncthreads();
    for (int idx = TID; idx < 64 * 128; idx += 256) {
      int j = idx >> 7, c = idx & 127;
      Cs[j][c] = cb[((cg << 6) + j) * 128 + c];
    }
    __syncthreads();
    float acc[4][4];
#pragma unroll
    for (int u = 0; u < 4; u++)
#pragma unroll
      for (int n = 0; n < 4; n++) acc[u][n] = 0.f;
    for (int c = 0; c < 128; c++) {
      float4 zv4 = *(const float4*)&Zs[c][pq << 2];
      float zv[4] = {zv4.x, zv4.y, zv4.z, zv4.w};
      float cv[4];
#pragma unroll
      for (int u = 0; u < 4; u++) cv[u] = Cs[j0 + u][c];
#pragma unroll
      for (int u = 0; u < 4; u++)
#pragma unroll
        for (int n = 0; n < 4; n++) acc[u][n] += zv[n] * cv[u];
    }
#pragma unroll
    for (int u = 0; u < 4; u++) {
      int code = (cg << 6) + j0 + u;
      float cs_ = csq[code];
#pragma unroll
      for (int n = 0; n < 4; n++) {
        float A = zsqs[(pq << 2) + n] + cs_;
        float B = 2.0f * acc[u][n];
        float d = A - B;
        if (d < best[n]) { best[n] = d; bidx[n] = code; }
      }
    }
  }
  __syncthreads();
#pragma unroll
  for (int n = 0; n < 4; n++) { bd[(pq << 2) + n][cq] = best[n]; bix[(pq << 2) + n][cq] = bidx[n]; }
  __syncthreads();
  if (TID < 64) {
    float bb = bd[TID][0];
    int bj = bix[TID][0];
    for (int q = 1; q < 16; q++) {
      float d = bd[TID][q];
      int j = bix[TID][q];
      if (d < bb || (d == bb && j < bj)) { bb = d; bj = j; }
    }
    codes[(b << 9) + t0 + TID] = bj;
  }
}

// ================= VQ bookkeeping =================
__global__ void count_k(const int* __restrict__ codes, float* __restrict__ counts) {
  int n = blockIdx.x * blockDim.x + TID;
  if (n < 16384) atomicAdd(&counts[codes[n]], 1.f);
}

__global__ __launch_bounds__(256) void gather_k(const float* __restrict__ cb, const int* __restrict__ codes,
                                                const float* __restrict__ zE, float* __restrict__ zQ,
                                                float* __restrict__ vqsum) {
  double part = 0.;
  const int total = 32 * 128 * 512;
  for (int idx = blockIdx.x * blockDim.x + TID; idx < total; idx += gridDim.x * blockDim.x) {
    int t = idx & 511;
    int c = (idx >> 9) & 127;
    int b = idx >> 16;
    int code = codes[(b << 9) + t];
    float q = cb[code * 128 + c];
    double d = (double)q - (double)zE[idx];
    zQ[idx] = q;
    part += d * d;
  }
  __shared__ double red[256];
  red[TID] = part;
  __syncthreads();
  for (int st = 128; st > 0; st >>= 1) {
    if (TID < st) red[TID] += red[TID + st];
    __syncthreads();
  }
  if (TID == 0) atomicAdd(vqsum, (float)red[0]);
}

// ================= decoder-only convs =================
__global__ __launch_bounds__(256) void conv_up_k(const float* __restrict__ in, const float* __restrict__ w,
                                                 const float* __restrict__ bias, float* __restrict__ out,
                                                 float* __restrict__ partOut) {
  int b = blockIdx.x / 17;
  int s0 = (blockIdx.x % 17) << 5;
  int o0 = blockIdx.y << 6;
  int tx = TID & 15, oy = TID >> 4;
  __shared__ float ins[16][36];
  __shared__ float wsl[16 * 512];
  float acc[2][4][4];
#pragma unroll
  for (int j = 0; j < 2; j++)
#pragma unroll
    for (int m = 0; m < 4; m++)
#pragma unroll
      for (int r = 0; r < 4; r++) acc[j][m][r] = 0.f;
  for (int ic0 = 0; ic0 < 256; ic0 += 16) {
    __syncthreads();
    for (int idx = TID; idx < 16 * 34; idx += 256) {
      int r = idx / 34, c = idx % 34;
      int s = s0 - 1 + c;
      float v = 0.f;
      if (s >= 0 && s < 512) v = in[(((size_t)((b << 8) + ic0 + r)) << 9) + s];
      ins[r][c] = v;
    }
    for (int idx = TID; idx < 8192; idx += 256) {
      int rr = idx & 3;
      int o = (idx >> 2) & 63;
      int h = (idx >> 8) & 1;
      int i = idx >> 9;
      wsl[idx] = w[(((size_t)(ic0 + i)) << 11) + ((size_t)(o0 + o) << 3) + (h << 2) + rr];
    }
    __syncthreads();
#pragma unroll 2
    for (int i = 0; i < 16; i++) {
      float x0 = ins[i][2 * tx], x1 = ins[i][2 * tx + 1], x2 = ins[i][2 * tx + 2];
#pragma unroll
      for (int m = 0; m < 4; m++) {
        int om = (oy << 2) + m;
        float4 wa4 = *(const float4*)&wsl[(i << 9) + (om << 2)];
        float4 wb4 = *(const float4*)&wsl[(i << 9) + 256 + (om << 2)];
        float wa[4] = {wa4.x, wa4.y, wa4.z, wa4.w};
        float wb[4] = {wb4.x, wb4.y, wb4.z, wb4.w};
#pragma unroll
        for (int r = 0; r < 4; r++) {
          acc[0][m][r] = fmaf(x1, wa[r], fmaf(x0, wb[r], acc[0][m][r]));
          acc[1][m][r] = fmaf(x2, wa[r], fmaf(x1, wb[r], acc[1][m][r]));
        }
      }
    }
  }
  float s1 = 0.f, s2 = 0.f;
#pragma unroll
  for (int j = 0; j < 2; j++) {
    int sS = s0 + (tx << 1) + j;
#pragma unroll
    for (int m = 0; m < 4; m++) {
      int o = o0 + (oy << 2) + m;
      float bv = bias[o];
#pragma unroll
      for (int r = 0; r < 4; r++) {
        int t = (sS << 2) + r - 2;
        if (t >= 0 && t < 2048) {
          float v = acc[j][m][r] + bv;
          out[(((size_t)((b << 8) + o)) << 11) + t] = v;
          s1 += v; s2 += v * v;
        }
      }
    }
  }
  __syncthreads();
  float* red = (float*)ins;
  red[TID] = s1; red[256 + TID] = s2;
  __syncthreads();
  for (int st = 64; st > 0; st >>= 1) {
    if ((TID & 127) < st) { red[TID] += red[TID + st]; red[256 + TID] += red[256 + TID + st]; }
    __syncthreads();
  }
  if ((TID & 127) == 0) {
    int g = (blockIdx.y << 1) + (TID >> 7);
    atomicAdd(&partOut[(((b << 3) + g) << 1)], red[TID]);
    atomicAdd(&partOut[(((b << 3) + g) << 1) + 1], red[256 + TID]);
  }
}

__global__ __launch_bounds__(256) void conv_out_k(const float* __restrict__ in, const float* __restrict__ wP,
                                                  const float* __restrict__ bias, float* __restrict__ xhat) {
  int b = blockIdx.x >> 5;
  int t0 = (blockIdx.x & 31) << 6;
  int tx = TID & 63, oy = TID >> 6;
  __shared__ float ins[32][68];
  __shared__ float wsl[32 * 144];
  float acc[9];
#pragma unroll
  for (int m = 0; m < 9; m++) acc[m] = 0.f;
  for (int ic0 = 0; ic0 < 256; ic0 += 32) {
    __syncthreads();
    for (int idx = TID; idx < 32 * 66; idx += 256) {
      int r = idx / 66, c = idx % 66;
      int t = t0 - 1 + c;
      float v = 0.f;
      if (t >= 0 && t < 2048) v = in[(((size_t)((b << 8) + ic0 + r)) << 11) + t];
      ins[r][c] = v;
    }
    for (int idx = TID; idx < 32 * 144; idx += 256) {
      wsl[idx] = wP[ic0 * 144 + idx];
    }
    __syncthreads();
#pragma unroll 4
    for (int i = 0; i < 32; i++) {
      float x0 = ins[i][tx], x1 = ins[i][tx + 1], x2 = ins[i][tx + 2];
#pragma unroll
      for (int m = 0; m < 9; m++) {
        int o = oy * 9 + m;
        float4 wv = *(const float4*)&wsl[(i * 36 + o) << 2];
        acc[m] = fmaf(wv.x, x0, fmaf(wv.y, x1, fmaf(wv.z, x2, acc[m])));
      }
    }
  }
  size_t orow = ((size_t)(b << 11) + t0 + tx) * 36;
#pragma unroll
  for (int m = 0; m < 9; m++) {
    int o = oy * 9 + m;
    xhat[orow + o] = acc[m] + bias[o];
  }
}

// ================= losses =================
__global__ __launch_bounds__(256) void loss_k(const float* __restrict__ x, const float* __restrict__ xh,
                                              const float* __restrict__ mask, float* __restrict__ scal) {
  float pos = 0.f, dir = 0.f, ms = 0.f;
  for (int n = blockIdx.x * blockDim.x + TID; n < 65536; n += gridDim.x * blockDim.x) {
    const float* xp = x + (size_t)n * 36;
    const float* hp = xh + (size_t)n * 36;
    float a[36], h[36];
#pragma unroll
    for (int d4 = 0; d4 < 36; d4 += 4) {
      *(float4*)&a[d4] = *(const float4*)&xp[d4];
      *(float4*)&h[d4] = *(const float4*)&hp[d4];
    }
#pragma unroll
    for (int d = 0; d < 36; d++) {
      if (d < 21 || (d >= 27 && d < 30)) {
        float df = h[d] - a[d];
        float ad = fabsf(df);
        pos += (ad < 1.f) ? 0.5f * df * df : ad - 0.5f;
      }
    }
    float mL = mask[2 * (size_t)n], mR = mask[2 * (size_t)n + 1];
    const int vb[4] = {21, 24, 30, 33};
    float mv[4] = {mL, mL, mR, mR};
#pragma unroll
    for (int v = 0; v < 4; v++) {
      int o = vb[v];
      float ax = a[o], ay = a[o + 1], az = a[o + 2];
      float hx = h[o], hy = h[o + 1], hz = h[o + 2];
      float an = sqrtf(ax * ax + ay * ay + az * az) + 1e-8f;
      float hn = sqrtf(hx * hx + hy * hy + hz * hz) + 1e-8f;
      float cs = (ax * hx + ay * hy + az * hz) / (an * hn);
      dir += (1.f - cs) * mv[v];
    }
    ms += 2.f * (mL + mR);
  }
  __shared__ float rp[256], rd[256], rm[256];
  rp[TID] = pos; rd[TID] = dir; rm[TID] = ms;
  __syncthreads();
  for (int st = 128; st > 0; st >>= 1) {
    if (TID < st) { rp[TID] += rp[TID + st]; rd[TID] += rd[TID + st]; rm[TID] += rm[TID + st]; }
    __syncthreads();
  }
  if (TID == 0) {
    atomicAdd(&scal[1], rp[0]);
    atomicAdd(&scal[2], rd[0]);
    atomicAdd(&scal[3], rm[0]);
  }
}

__global__ __launch_bounds__(256) void finalize_k(const float* __restrict__ counts, const float* __restrict__ scal,
                                                  float* __restrict__ tail) {
  __shared__ float red[256];
  float s = 0.f;
  for (int j = TID; j < 1024; j += 256) {
    float avg = counts[j] * (1.f / 16384.f);
    s += avg * logf(avg + 1e-10f);
  }
  red[TID] = s;
  __syncthreads();
  for (int st = 128; st > 0; st >>= 1) {
    if (TID < st) red[TID] += red[TID + st];
    __syncthreads();
  }
  if (TID == 0) {
    tail[0] = 1.25f * scal[0] * (1.f / 2097152.f);
    tail[1] = expf(-red[0]);
    tail[2] = scal[1] * (1.f / 65536.f);
    tail[3] = scal[2] / fmaxf(scal[3], 1.f);
  }
}

__global__ void codesf_k(const int* __restrict__ codes, float* __restrict__ o) {
  int n = blockIdx.x * blockDim.x + TID;
  if (n < 16384) o[n] = (float)codes[n];
}

// ================= host =================
extern "C" void kernel_launch(void* const* d_in, const int* in_sizes, int n_in,
                              void* d_out, int out_size, void* d_ws, size_t ws_size,
                              hipStream_t stream) {
  const float* x = (const float*)d_in[0];
  const float* mask = (const float*)d_in[1];
  const float* enc_in_w = (const float*)d_in[2];
  const float* enc_in_b = (const float*)d_in[3];
  const float* enc_gn1_g = (const float*)d_in[4];
  const float* enc_gn1_b = (const float*)d_in[5];
  const float* enc_c1_w = (const float*)d_in[6];
  const float* enc_c1_b = (const float*)d_in[7];
  const float* enc_gn2_g = (const float*)d_in[8];
  const float* enc_gn2_b = (const float*)d_in[9];
  const float* enc_c2_w = (const float*)d_in[10];
  const float* enc_c2_b = (const float*)d_in[11];
  const float* down_w = (const float*)d_in[12];
  const float* down_b = (const float*)d_in[13];
  const float* enc_out_w = (const float*)d_in[14];
  const float* enc_out_b = (const float*)d_in[15];
  const float* codebook = (const float*)d_in[16];
  const float* dec_in_w = (const float*)d_in[17];
  const float* dec_in_b = (const float*)d_in[18];
  const float* up_w = (const float*)d_in[19];
  const float* up_b = (const float*)d_in[20];
  const float* dec_gn1_g = (const float*)d_in[21];
  const float* dec_gn1_b = (const float*)d_in[22];
  const float* dec_c1_w = (const float*)d_in[23];
  const float* dec_c1_b = (const float*)d_in[24];
  const float* dec_gn2_g = (const float*)d_in[25];
  const float* dec_gn2_b = (const float*)d_in[26];
  const float* dec_c2_w = (const float*)d_in[27];
  const float* dec_c2_b = (const float*)d_in[28];
  const float* dec_out_w = (const float*)d_in[29];
  const float* dec_out_b = (const float*)d_in[30];

  char* W = (char*)d_ws;
  float* zE = (float*)(W + 0);                        // 8,388,608
  float* zQ = (float*)(W + 8388608);                  // 8,388,608
  int* codes = (int*)(W + 16777216);                  // 65,536
  float* counts = (float*)(W + 16842752);             // 4,096 (1024 f)
  float* scal = (float*)(W + 16846848);               // 32
  float* stats = (float*)(W + 16846880);              // 18 x 512 f = 36,864 B
  float* csq = (float*)(W + 16883744);                // 4,096
  float* wf_enc_in = (float*)(W + 16887840);          // 110,592
  float* wf_enc_c1 = (float*)(W + 16998432);          // 3,145,728
  float* wf_enc_c2 = (float*)(W + 20144160);          // 3,145,728
  float* wf_down = (float*)(W + 23289888);            // 2,097,152
  float* wf_enc_out = (float*)(W + 25387040);         // 131,072
  float* wf_dec_in = (float*)(W + 25518112);          // 131,072
  float* wf_dec_c1 = (float*)(W + 25649184);          // 3,145,728
  float* wf_dec_c2 = (float*)(W + 28794912);          // 3,145,728
  float* wf_dec_out = (float*)(W + 31940640);         // 147,456
  float* f0 = (float*)(W + 50331648);
  float* f2 = (float*)(W + 50331648 + (size_t)67108864);
  float* dech = (float*)(W + 50331648 + 2 * (size_t)67108864);

  dim3 blk(256);
  zero_k<<<dim3(41), blk, 0, stream>>>(counts, 1024 + 8 + 9216);
  perm_oik_iko<<<dim3(128), blk, 0, stream>>>(enc_in_w, wf_enc_in, 1, 256, 36, 3);
  perm_oik_iko<<<dim3(1024), blk, 0, stream>>>(enc_c1_w, wf_enc_c1, 4, 256, 256, 3);
  perm_oik_iko<<<dim3(1024), blk, 0, stream>>>(enc_c2_w, wf_enc_c2, 4, 256, 256, 3);
  perm_oik_iko<<<dim3(1024), blk, 0, stream>>>(down_w, wf_down, 1, 256, 256, 8);
  perm_oik_iko<<<dim3(128), blk, 0, stream>>>(enc_out_w, wf_enc_out, 1, 128, 256, 1);
  perm_oik_iko<<<dim3(128), blk, 0, stream>>>(dec_in_w, wf_dec_in, 1, 256, 128, 1);
  perm_oik_iko<<<dim3(1024), blk, 0, stream>>>(dec_c1_w, wf_dec_c1, 4, 256, 256, 3);
  perm_oik_iko<<<dim3(1024), blk, 0, stream>>>(dec_c2_w, wf_dec_c2, 4, 256, 256, 3);
  perm_decout<<<dim3(64), blk, 0, stream>>>(dec_out_w, wf_dec_out);
  csq_f32<<<dim3(4), blk, 0, stream>>>(codebook, csq);

  // ---- encoder (fp32), whole batch; stats slots 0..7 ----
  conv_in_k<<<dim3(NB * 32, 4), blk, 0, stream>>>(x, wf_enc_in, enc_in_b, f0, stats + 0 * 512);
  for (int i = 0; i < 4; i++) {
    float* sIn = stats + (2 * i) * 512;
    float* sMid = stats + (2 * i + 1) * 512;
    float* sOut = (i < 3) ? stats + (2 * i + 2) * 512 : nullptr;  // last layer: stats unused
    conv3_gn_k<<<dim3(NB * 8, 2), blk, 0, stream>>>(f0, sIn, enc_gn1_g + i * 256, enc_gn1_b + i * 256,
                                                    wf_enc_c1 + i * 196608, enc_c1_b + i * 256, nullptr, f2, sMid);
    conv3_gn_k<<<dim3(NB * 8, 2), blk, 0, stream>>>(f2, sMid, enc_gn2_g + i * 256, enc_gn2_b + i * 256,
                                                    wf_enc_c2 + i * 196608, enc_c2_b + i * 256, f0, f0, sOut);
  }
  conv_down_k<<<dim3(NB * 8, 4), blk, 0, stream>>>(f0, wf_down, down_b, f2);
  conv1x1_k<<<dim3(NB * 8, 2), blk, 0, stream>>>(f2, wf_enc_out, enc_out_b, zE, 256, 128);

  // ---- quantize ----
  vq_tiled<<<dim3(256), blk, 0, stream>>>(zE, codebook, csq, codes);
  count_k<<<dim3(64), blk, 0, stream>>>(codes, counts);
  gather_k<<<dim3(512), blk, 0, stream>>>(codebook, codes, zE, zQ, &scal[0]);

  // ---- decoder (fp32), whole batch; stats slots 9..16 ----
  float* xhat = (float*)d_out;
  conv1x1_k<<<dim3(NB * 8, 4), blk, 0, stream>>>(zQ, wf_dec_in, dec_in_b, dech, 128, 256);
  conv_up_k<<<dim3(NB * 17, 4), blk, 0, stream>>>(dech, up_w, up_b, f0, stats + 9 * 512);
  for (int i = 0; i < 4; i++) {
    float* sIn = stats + (9 + 2 * i) * 512;
    float* sMid = stats + (10 + 2 * i) * 512;
    float* sOut = (i < 3) ? stats + (11 + 2 * i) * 512 : nullptr;  // last layer: stats unused
    conv3_gn_k<<<dim3(NB * 8, 2), blk, 0, stream>>>(f0, sIn, dec_gn1_g + i * 256, dec_gn1_b + i * 256,
                                                    wf_dec_c1 + i * 196608, dec_c1_b + i * 256, nullptr, f2, sMid);
    conv3_gn_k<<<dim3(NB * 8, 2), blk, 0, stream>>>(f2, sMid, dec_gn2_g + i * 256, dec_gn2_b + i * 256,
                                                    wf_dec_c2 + i * 196608, dec_c2_b + i * 256, f0, f0, sOut);
  }
  conv_out_k<<<dim3(NB * 32), blk, 0, stream>>>(f0, wf_dec_out, dec_out_b, xhat);

  // ---- losses / scalars ----
  loss_k<<<dim3(256), blk, 0, stream>>>(x, xhat, mask, scal);
  finalize_k<<<dim3(1), blk, 0, stream>>>(counts, scal, (float*)d_out + 2375680);
  codesf_k<<<dim3(64), blk, 0, stream>>>(codes, (float*)d_out + 2359296);
}

// Round 14
// 6653.444 us; speedup vs baseline: 1.2114x; 1.0016x over previous
//
#include <hip/hip_runtime.h>
#include <cstddef>
#include <cstdint>

// VQ-VAE 1D forward — full fp32 pipeline.
// Codes: reference argmin follows fp32 dist = fl(zsq+csq) - fl(2*zc), first-index ties.
// vq_tiled distance math is BYTE-IDENTICAL to the r7-passing kernel (epilogue has
// counts/float-codes bookkeeping only). Conv chains keep r12 fmaf expressions.
// R14: fixes r13's swizzle read bug — reads now use ro = (oy<<2)+((oy>>3)<<2) to match
// the write permutation po = o4 + 4*(o4>>5). All else identical to r13.
// d_out: x_hat (B,T,36) | codes as float (B,512) | [loss_vq, perplexity, loss_pos, loss_dir]

#define TID ((int)threadIdx.x)
#define NB 32  // whole batch, single pass

__device__ __forceinline__ float silu_f(float y) { return y / (1.f + expf(-y)); }

// ================= weight prep =================
__global__ void perm_oik_iko(const float* __restrict__ src, float* __restrict__ dst,
                             int R, int O, int I, int K) {
  int n = R * O * I * K;
  for (int idx = blockIdx.x * blockDim.x + TID; idx < n; idx += gridDim.x * blockDim.x) {
    int o = idx % O;
    int k = (idx / O) % K;
    int i = (idx / (O * K)) % I;
    int r = idx / (O * K * I);
    dst[idx] = src[((r * O + o) * I + i) * K + k];
  }
}

__global__ void perm_decout(const float* __restrict__ src, float* __restrict__ dst) {
  int n = 256 * 36 * 4;
  for (int idx = blockIdx.x * blockDim.x + TID; idx < n; idx += gridDim.x * blockDim.x) {
    int k = idx & 3;
    int o = (idx >> 2) % 36;
    int i = idx / 144;
    dst[idx] = (k < 3) ? src[(o * 256 + i) * 3 + k] : 0.f;
  }
}

__global__ void zero_k(float* p, int n) {
  int i = blockIdx.x * blockDim.x + TID;
  if (i < n) p[i] = 0.f;
}

// csq[j] = fp32 sequential sum of fl(c*c)
__global__ void csq_f32(const float* __restrict__ cb, float* __restrict__ csq) {
  int j = blockIdx.x * blockDim.x + TID;
  if (j < 1024) {
    float s = 0.f;
    for (int c = 0; c < 128; c++) { float v = cb[j * 128 + c]; s += v * v; }
    csq[j] = s;
  }
}

// ================= fp32 convs =================
// input conv 36->256, k=3, with GN-stats epilogue. grid=(NB*32,4)
__global__ __launch_bounds__(256) void conv_in_k(const float* __restrict__ x, const float* __restrict__ wT,
                                                 const float* __restrict__ bias, float* __restrict__ out,
                                                 float* __restrict__ partOut) {
  int b = blockIdx.x >> 5;
  int t0 = (blockIdx.x & 31) << 6;
  int o0 = blockIdx.y << 6;
  int tx = TID & 15, oy = TID >> 4;
  __shared__ float ins[36][68];
  __shared__ float wsl[36 * 192];
  for (int idx = TID; idx < 36 * 66; idx += 256) {
    int i = idx % 36, c = idx / 36;
    int t = t0 - 1 + c;
    float v = 0.f;
    if (t >= 0 && t < 2048) v = x[((size_t)(b * 2048 + t)) * 36 + i];
    ins[i][c] = v;
  }
  for (int idx = TID; idx < 36 * 192; idx += 256) {
    int o = idx & 63;
    int kk = (idx >> 6) % 3;
    int i = idx / 192;
    wsl[idx] = wT[(i * 3 + kk) * 256 + o0 + o];
  }
  __syncthreads();
  float acc[4][4];
#pragma unroll
  for (int m = 0; m < 4; m++)
#pragma unroll
    for (int n = 0; n < 4; n++) acc[m][n] = 0.f;
  for (int i = 0; i < 36; i++) {
    float xv[6];
    float4 x4 = *(const float4*)&ins[i][tx << 2];
    xv[0] = x4.x; xv[1] = x4.y; xv[2] = x4.z; xv[3] = x4.w;
    xv[4] = ins[i][(tx << 2) + 4];
    xv[5] = ins[i][(tx << 2) + 5];
    const float* wrow = &wsl[i * 192];
    float wv[3][4];
    *(float4*)wv[0] = *(const float4*)&wrow[oy << 2];
    *(float4*)wv[1] = *(const float4*)&wrow[64 + (oy << 2)];
    *(float4*)wv[2] = *(const float4*)&wrow[128 + (oy << 2)];
#pragma unroll
    for (int m = 0; m < 4; m++)
#pragma unroll
      for (int n = 0; n < 4; n++)
        acc[m][n] = fmaf(wv[0][m], xv[n], fmaf(wv[1][m], xv[n + 1], fmaf(wv[2][m], xv[n + 2], acc[m][n])));
  }
  int obase = o0 + (oy << 2);
  float s1 = 0.f, s2 = 0.f;
#pragma unroll
  for (int m = 0; m < 4; m++) {
    int o = obase + m;
    float bv = bias[o];
    size_t rowo = (((size_t)((b << 8) + o)) << 11) + t0 + (tx << 2);
#pragma unroll
    for (int n = 0; n < 4; n++) {
      float v = acc[m][n] + bv;
      out[rowo + n] = v;
      s1 += v; s2 += v * v;
    }
  }
  __syncthreads();
  float* red = (float*)ins;
  red[TID] = s1; red[256 + TID] = s2;
  __syncthreads();
  for (int st = 64; st > 0; st >>= 1) {
    if ((TID & 127) < st) { red[TID] += red[TID + st]; red[256 + TID] += red[256 + TID + st]; }
    __syncthreads();
  }
  if ((TID & 127) == 0) {
    int g = (blockIdx.y << 1) + (TID >> 7);
    atomicAdd(&partOut[(((b << 3) + g) << 1)], red[TID]);
    atomicAdd(&partOut[(((b << 3) + g) << 1) + 1], red[256 + TID]);
  }
}

// k=3 conv 256->256 with fused GN+SiLU input (stats from partIn) + optional stats epilogue.
// o-tile 128, t-tile 256, ic-chunk 16, fmaf chains. w-stage swizzled:
// write po = o4 + 4*(o4>>5); read ro = (oy<<2) + 4*(oy>>3)  [matches po]. grid=(NB*8, 2).
#define WROW 140
__global__ __launch_bounds__(256, 2) void conv3_gn_k(const float* __restrict__ in, const float* __restrict__ partIn,
                                                     const float* __restrict__ gamma, const float* __restrict__ beta,
                                                     const float* __restrict__ wT, const float* __restrict__ bias,
                                                     const float* __restrict__ src, float* __restrict__ out,
                                                     float* __restrict__ partOut) {
  int b = blockIdx.x >> 3;
  int t0 = (blockIdx.x & 7) << 8;
  int o0 = blockIdx.y << 7;
  int tx = TID & 15, oy = TID >> 4;
  __shared__ float ins[16][264];           // 260 used
  __shared__ float wsl[3 * 16 * WROW];     // swizzled weight rows
  float acc[2][4][16];
#pragma unroll
  for (int h = 0; h < 2; h++)
#pragma unroll
    for (int m = 0; m < 4; m++)
#pragma unroll
      for (int n = 0; n < 16; n++) acc[h][m][n] = 0.f;
  const int ro = (oy << 2) + ((oy >> 3) << 2);  // swizzled read offset for o4 = oy<<2
  for (int ic0 = 0; ic0 < 256; ic0 += 16) {
    int g = ic0 >> 5;
    const float* pp = partIn + (((size_t)((b << 3) + g)) << 1);
    float s1 = pp[0], s2 = pp[1];
    float mu = s1 * (1.f / 65536.f);
    float var = s2 * (1.f / 65536.f) - mu * mu;
    float rs = rsqrtf(var + 1e-5f);
    __syncthreads();
    // stage x: row r = oy, 16 lanes per row, per-row GN constants hoisted
    {
      int ch = ic0 + oy;
      float a = rs * gamma[ch];
      float bb = beta[ch] - mu * a;
      const float* grow = in + (((size_t)((b << 8) + ch)) << 11);
#pragma unroll
      for (int q = 0; q < 17; q++) {
        int c = tx + (q << 4);
        if (c < 260) {
          int t = t0 - 1 + c;
          float v = 0.f;
          if (t >= 0 && t < 2048) {
            float h = grow[t];
            float y = h * a + bb;
            v = y / (1.f + expf(-y));
          }
          ins[oy][c] = v;
        }
      }
    }
    // stage w (swizzled): po = o4 + 4*(o4>>5)
    for (int idx4 = TID; idx4 < 1536; idx4 += 256) {
      int o4 = (idx4 & 31) << 2;
      int i = (idx4 >> 5) & 15;
      int kk = idx4 >> 9;
      int po = o4 + ((o4 >> 5) << 2);
      *(float4*)&wsl[((kk << 4) + i) * WROW + po] =
          *(const float4*)&wT[((ic0 + i) * 3 + kk) * 256 + o0 + o4];
    }
    __syncthreads();
    for (int i = 0; i < 16; i++) {
      float xq[4][6];
#pragma unroll
      for (int q = 0; q < 4; q++) {
        *(float4*)&xq[q][0] = *(const float4*)&ins[i][(q << 6) + (tx << 2)];
        *(float2*)&xq[q][4] = *(const float2*)&ins[i][(q << 6) + (tx << 2) + 4];
      }
      float wv[3][4], wb[3][4];
#pragma unroll
      for (int kk = 0; kk < 3; kk++) {
        const float* wrow = &wsl[((kk << 4) + i) * WROW];
        *(float4*)wv[kk] = *(const float4*)&wrow[ro];         // o4 = oy<<2, po = ro
        *(float4*)wb[kk] = *(const float4*)&wrow[72 + ro];    // o4 = 64+(oy<<2), po = 72+ro
      }
#pragma unroll
      for (int m = 0; m < 4; m++)
#pragma unroll
        for (int q = 0; q < 4; q++)
#pragma unroll
          for (int n = 0; n < 4; n++) {
            acc[0][m][(q << 2) + n] =
                fmaf(wv[0][m], xq[q][n], fmaf(wv[1][m], xq[q][n + 1], fmaf(wv[2][m], xq[q][n + 2], acc[0][m][(q << 2) + n])));
            acc[1][m][(q << 2) + n] =
                fmaf(wb[0][m], xq[q][n], fmaf(wb[1][m], xq[q][n + 1], fmaf(wb[2][m], xq[q][n + 2], acc[1][m][(q << 2) + n])));
          }
    }
  }
  float sh1[2] = {0.f, 0.f}, sh2[2] = {0.f, 0.f};
#pragma unroll
  for (int h = 0; h < 2; h++)
#pragma unroll
    for (int m = 0; m < 4; m++) {
      int o = o0 + (h << 6) + (oy << 2) + m;
      float bv = bias[o];
      size_t rowbase = (((size_t)((b << 8) + o)) << 11) + t0 + (tx << 2);
#pragma unroll
      for (int q = 0; q < 4; q++) {
        size_t row = rowbase + (q << 6);
#pragma unroll
        for (int n = 0; n < 4; n++) {
          float v = acc[h][m][(q << 2) + n] + bv;
          if (src) v += src[row + n];
          out[row + n] = v;
          sh1[h] += v; sh2[h] += v * v;
        }
      }
    }
  if (partOut) {
    __syncthreads();
    float* red = (float*)ins;
#pragma unroll
    for (int h = 0; h < 2; h++) {
      red[TID] = sh1[h]; red[256 + TID] = sh2[h];
      __syncthreads();
      for (int st = 64; st > 0; st >>= 1) {
        if ((TID & 127) < st) { red[TID] += red[TID + st]; red[256 + TID] += red[256 + TID + st]; }
        __syncthreads();
      }
      if ((TID & 127) == 0) {
        int g = (blockIdx.y << 2) + (h << 1) + (TID >> 7);
        atomicAdd(&partOut[(((b << 3) + g) << 1)], red[TID]);
        atomicAdd(&partOut[(((b << 3) + g) << 1) + 1], red[256 + TID]);
      }
      __syncthreads();
    }
  }
}

// down conv k=8 stride 4, Tout=512. Lane-interleaved outputs (to0+tx+16u) so x reads
// are stride-4 (conflict-free). grid=(NB*8,4)
__global__ __launch_bounds__(256) void conv_down_k(const float* __restrict__ in, const float* __restrict__ wT,
                                                   const float* __restrict__ bias, float* __restrict__ out) {
  int b = blockIdx.x >> 3;
  int to0 = (blockIdx.x & 7) << 6;
  int o0 = blockIdx.y << 6;
  int tx = TID & 15, oy = TID >> 4;
  __shared__ float ins[16][264];
  __shared__ float wsl[16 * 512];
  float acc[4][4];  // [m][u]
#pragma unroll
  for (int m = 0; m < 4; m++)
#pragma unroll
    for (int u = 0; u < 4; u++) acc[m][u] = 0.f;
  for (int ic0 = 0; ic0 < 256; ic0 += 16) {
    __syncthreads();
    for (int idx = TID; idx < 16 * 260; idx += 256) {
      int r = idx / 260, c = idx % 260;
      int s = (to0 << 2) - 2 + c;
      float v = 0.f;
      if (s >= 0 && s < 2048) v = in[(((size_t)((b << 8) + ic0 + r)) << 11) + s];
      ins[r][c] = v;
    }
    for (int idx = TID; idx < 16 * 512; idx += 256) {
      int o = idx & 63;
      int kk = (idx >> 6) & 7;
      int i = idx >> 9;
      wsl[idx] = wT[((ic0 + i) * 8 + kk) * 256 + o0 + o];
    }
    __syncthreads();
#pragma unroll 2
    for (int i = 0; i < 16; i++) {
      float xv[4][8];
#pragma unroll
      for (int u = 0; u < 4; u++) {
        *(float4*)&xv[u][0] = *(const float4*)&ins[i][(u << 6) + (tx << 2)];
        *(float4*)&xv[u][4] = *(const float4*)&ins[i][(u << 6) + (tx << 2) + 4];
      }
      float wv[8][4];
#pragma unroll
      for (int kk = 0; kk < 8; kk++) *(float4*)wv[kk] = *(const float4*)&wsl[(i << 9) + (kk << 6) + (oy << 2)];
#pragma unroll
      for (int u = 0; u < 4; u++)
#pragma unroll
        for (int kk = 0; kk < 8; kk++) {
          float xval = xv[u][kk];
#pragma unroll
          for (int m = 0; m < 4; m++) acc[m][u] = fmaf(wv[kk][m], xval, acc[m][u]);
        }
    }
  }
  int obase = o0 + (oy << 2);
#pragma unroll
  for (int m = 0; m < 4; m++) {
    int o = obase + m;
    float bv = bias[o];
    size_t rowo = (((size_t)((b << 8) + o)) << 9) + to0 + tx;
#pragma unroll
    for (int u = 0; u < 4; u++) out[rowo + (u << 4)] = acc[m][u] + bv;
  }
}

// 1x1 conv, T=512. grid=(NB*8, O/64)
__global__ __launch_bounds__(256) void conv1x1_k(const float* __restrict__ in, const float* __restrict__ wIO,
                                                 const float* __restrict__ bias, float* __restrict__ out,
                                                 int Kc, int O) {
  int b = blockIdx.x >> 3;
  int t0 = (blockIdx.x & 7) << 6;
  int o0 = blockIdx.y << 6;
  int tx = TID & 15, oy = TID >> 4;
  __shared__ float xs[32][64];
  __shared__ float wsd[32][64];
  float acc[4][4];
#pragma unroll
  for (int m = 0; m < 4; m++)
#pragma unroll
    for (int n = 0; n < 4; n++) acc[m][n] = 0.f;
  for (int ic0 = 0; ic0 < Kc; ic0 += 32) {
    __syncthreads();
    for (int idx = TID; idx < 2048; idx += 256) {
      int r = idx >> 6, c = idx & 63;
      xs[r][c] = in[((size_t)(b * Kc + ic0 + r) << 9) + t0 + c];
      wsd[r][c] = wIO[(ic0 + r) * O + o0 + c];
    }
    __syncthreads();
#pragma unroll 8
    for (int i = 0; i < 32; i++) {
      float4 xvv = *(const float4*)&xs[i][tx << 2];
      float4 wvv = *(const float4*)&wsd[i][oy << 2];
      float xv[4] = {xvv.x, xvv.y, xvv.z, xvv.w};
      float wv[4] = {wvv.x, wvv.y, wvv.z, wvv.w};
#pragma unroll
      for (int m = 0; m < 4; m++)
#pragma unroll
        for (int n = 0; n < 4; n++) acc[m][n] = fmaf(wv[m], xv[n], acc[m][n]);
    }
  }
#pragma unroll
  for (int m = 0; m < 4; m++) {
    int o = o0 + (oy << 2) + m;
    float bv = bias[o];
    size_t rowo = ((size_t)(b * O + o) << 9) + t0 + (tx << 2);
#pragma unroll
    for (int n = 0; n < 4; n++) out[rowo + n] = acc[m][n] + bv;
  }
}

// ===== VQ tiled: distance math BYTE-IDENTICAL to r7-passing kernel.
// Epilogue: counts atomicAdd + float-codes write (post-argmin bookkeeping only).
__global__ __launch_bounds__(256) void vq_tiled(const float* __restrict__ zE,
                                                const float* __restrict__ cb,
                                                const float* __restrict__ csq,
                                                int* __restrict__ codes,
                                                float* __restrict__ counts,
                                                float* __restrict__ codesF) {
  int b = blockIdx.x >> 3;
  int t0 = (blockIdx.x & 7) << 6;
  int cq = TID & 15, pq = TID >> 4;
  __shared__ float Zs[128][66];
  __shared__ float Cs[64][129];
  __shared__ float zsqs[64];
  __shared__ float bd[64][17];
  __shared__ int bix[64][17];
  for (int idx = TID; idx < 128 * 64; idx += 256) {
    int c = idx >> 6, p = idx & 63;
    Zs[c][p] = zE[((size_t)(b * 128 + c) << 9) + t0 + p];
  }
  __syncthreads();
  if (TID < 64) {
    float s = 0.f;
    for (int c = 0; c < 128; c++) { float v = Zs[c][TID]; s += v * v; }
    zsqs[TID] = s;
  }
  float best[4];
  int bidx[4];
#pragma unroll
  for (int n = 0; n < 4; n++) { best[n] = 3.4e38f; bidx[n] = 0; }
  const int j0 = cq << 2;
  for (int cg = 0; cg < 16; cg++) {
    __syncthreads();
    for (int idx = TID; idx < 64 * 128; idx += 256) {
      int j = idx >> 7, c = idx & 127;
      Cs[j][c] = cb[((cg << 6) + j) * 128 + c];
    }
    __syncthreads();
    float acc[4][4];
#pragma unroll
    for (int u = 0; u < 4; u++)
#pragma unroll
      for (int n = 0; n < 4; n++) acc[u][n] = 0.f;
    for (int c = 0; c < 128; c++) {
      float4 zv4 = *(const float4*)&Zs[c][pq << 2];
      float zv[4] = {zv4.x, zv4.y, zv4.z, zv4.w};
      float cv[4];
#pragma unroll
      for (int u = 0; u < 4; u++) cv[u] = Cs[j0 + u][c];
#pragma unroll
      for (int u = 0; u < 4; u++)
#pragma unroll
        for (int n = 0; n < 4; n++) acc[u][n] += zv[n] * cv[u];
    }
#pragma unroll
    for (int u = 0; u < 4; u++) {
      int code = (cg << 6) + j0 + u;
      float cs_ = csq[code];
#pragma unroll
      for (int n = 0; n < 4; n++) {
        float A = zsqs[(pq << 2) + n] + cs_;
        float B = 2.0f * acc[u][n];
        float d = A - B;
        if (d < best[n]) { best[n] = d; bidx[n] = code; }
      }
    }
  }
  __syncthreads();
#pragma unroll
  for (int n = 0; n < 4; n++) { bd[(pq << 2) + n][cq] = best[n]; bix[(pq << 2) + n][cq] = bidx[n]; }
  __syncthreads();
  if (TID < 64) {
    float bb = bd[TID][0];
    int bj = bix[TID][0];
    for (int q = 1; q < 16; q++) {
      float d = bd[TID][q];
      int j = bix[TID][q];
      if (d < bb || (d == bb && j < bj)) { bb = d; bj = j; }
    }
    int n = (b << 9) + t0 + TID;
    codes[n] = bj;
    codesF[n] = (float)bj;
    atomicAdd(&counts[bj], 1.f);
  }
}

// ================= VQ bookkeeping =================
__global__ __launch_bounds__(256) void gather_k(const float* __restrict__ cb, const int* __restrict__ codes,
                                                const float* __restrict__ zE, float* __restrict__ zQ,
                                                float* __restrict__ vqsum) {
  double part = 0.;
  const int total = 32 * 128 * 512;
  for (int idx = blockIdx.x * blockDim.x + TID; idx < total; idx += gridDim.x * blockDim.x) {
    int t = idx & 511;
    int c = (idx >> 9) & 127;
    int b = idx >> 16;
    int code = codes[(b << 9) + t];
    float q = cb[code * 128 + c];
    double d = (double)q - (double)zE[idx];
    zQ[idx] = q;
    part += d * d;
  }
  __shared__ double red[256];
  red[TID] = part;
  __syncthreads();
  for (int st = 128; st > 0; st >>= 1) {
    if (TID < st) red[TID] += red[TID + st];
    __syncthreads();
  }
  if (TID == 0) atomicAdd(vqsum, (float)red[0]);
}

// ================= decoder-only convs =================
// transposed conv up, s-tile 64 (j<4), with GN-stats epilogue. grid=(NB*9,4)
__global__ __launch_bounds__(256) void conv_up_k(const float* __restrict__ in, const float* __restrict__ w,
                                                 const float* __restrict__ bias, float* __restrict__ out,
                                                 float* __restrict__ partOut) {
  int b = blockIdx.x / 9;
  int s0 = (blockIdx.x % 9) << 6;
  int o0 = blockIdx.y << 6;
  int tx = TID & 15, oy = TID >> 4;
  __shared__ float ins[16][68];
  __shared__ float wsl[16 * 512];
  float acc[4][4][4];  // [j][m][r]
#pragma unroll
  for (int j = 0; j < 4; j++)
#pragma unroll
    for (int m = 0; m < 4; m++)
#pragma unroll
      for (int r = 0; r < 4; r++) acc[j][m][r] = 0.f;
  for (int ic0 = 0; ic0 < 256; ic0 += 16) {
    __syncthreads();
    for (int idx = TID; idx < 16 * 66; idx += 256) {
      int r = idx / 66, c = idx % 66;
      int s = s0 - 1 + c;
      float v = 0.f;
      if (s >= 0 && s < 512) v = in[(((size_t)((b << 8) + ic0 + r)) << 9) + s];
      ins[r][c] = v;
    }
    for (int idx = TID; idx < 8192; idx += 256) {
      int rr = idx & 3;
      int o = (idx >> 2) & 63;
      int h = (idx >> 8) & 1;
      int i = idx >> 9;
      wsl[idx] = w[(((size_t)(ic0 + i)) << 11) + ((size_t)(o0 + o) << 3) + (h << 2) + rr];
    }
    __syncthreads();
#pragma unroll 2
    for (int i = 0; i < 16; i++) {
      float xv[5];
#pragma unroll
      for (int q = 0; q < 5; q++) xv[q] = ins[i][(tx << 2) + q];
#pragma unroll
      for (int m = 0; m < 4; m++) {
        int om = (oy << 2) + m;
        float4 wa4 = *(const float4*)&wsl[(i << 9) + (om << 2)];
        float4 wb4 = *(const float4*)&wsl[(i << 9) + 256 + (om << 2)];
        float wa[4] = {wa4.x, wa4.y, wa4.z, wa4.w};
        float wb[4] = {wb4.x, wb4.y, wb4.z, wb4.w};
#pragma unroll
        for (int j = 0; j < 4; j++)
#pragma unroll
          for (int r = 0; r < 4; r++)
            acc[j][m][r] = fmaf(xv[j + 1], wa[r], fmaf(xv[j], wb[r], acc[j][m][r]));
      }
    }
  }
  float s1 = 0.f, s2 = 0.f;
#pragma unroll
  for (int j = 0; j < 4; j++) {
    int sS = s0 + (tx << 2) + j;
#pragma unroll
    for (int m = 0; m < 4; m++) {
      int o = o0 + (oy << 2) + m;
      float bv = bias[o];
#pragma unroll
      for (int r = 0; r < 4; r++) {
        int t = (sS << 2) + r - 2;
        if (t >= 0 && t < 2048) {
          float v = acc[j][m][r] + bv;
          out[(((size_t)((b << 8) + o)) << 11) + t] = v;
          s1 += v; s2 += v * v;
        }
      }
    }
  }
  __syncthreads();
  float* red = (float*)ins;
  red[TID] = s1; red[256 + TID] = s2;
  __syncthreads();
  for (int st = 64; st > 0; st >>= 1) {
    if ((TID & 127) < st) { red[TID] += red[TID + st]; red[256 + TID] += red[256 + TID + st]; }
    __syncthreads();
  }
  if ((TID & 127) == 0) {
    int g = (blockIdx.y << 1) + (TID >> 7);
    atomicAdd(&partOut[(((b << 3) + g) << 1)], red[TID]);
    atomicAdd(&partOut[(((b << 3) + g) << 1) + 1], red[256 + TID]);
  }
}

__global__ __launch_bounds__(256) void conv_out_k(const float* __restrict__ in, const float* __restrict__ wP,
                                                  const float* __restrict__ bias, float* __restrict__ xhat) {
  int b = blockIdx.x >> 5;
  int t0 = (blockIdx.x & 31) << 6;
  int tx = TID & 63, oy = TID >> 6;
  __shared__ float ins[32][68];
  __shared__ float wsl[32 * 144];
  float acc[9];
#pragma unroll
  for (int m = 0; m < 9; m++) acc[m] = 0.f;
  for (int ic0 = 0; ic0 < 256; ic0 += 32) {
    __syncthreads();
    for (int idx = TID; idx < 32 * 66; idx += 256) {
      int r = idx / 66, c = idx % 66;
      int t = t0 - 1 + c;
      float v = 0.f;
      if (t >= 0 && t < 2048) v = in[(((size_t)((b << 8) + ic0 + r)) << 11) + t];
      ins[r][c] = v;
    }
    for (int idx = TID; idx < 32 * 144; idx += 256) {
      wsl[idx] = wP[ic0 * 144 + idx];
    }
    __syncthreads();
#pragma unroll 4
    for (int i = 0; i < 32; i++) {
      float x0 = ins[i][tx], x1 = ins[i][tx + 1], x2 = ins[i][tx + 2];
#pragma unroll
      for (int m = 0; m < 9; m++) {
        int o = oy * 9 + m;
        float4 wv = *(const float4*)&wsl[(i * 36 + o) << 2];
        acc[m] = fmaf(wv.x, x0, fmaf(wv.y, x1, fmaf(wv.z, x2, acc[m])));
      }
    }
  }
  size_t orow = ((size_t)(b << 11) + t0 + tx) * 36;
#pragma unroll
  for (int m = 0; m < 9; m++) {
    int o = oy * 9 + m;
    xhat[orow + o] = acc[m] + bias[o];
  }
}

// ================= losses =================
__global__ __launch_bounds__(256) void loss_k(const float* __restrict__ x, const float* __restrict__ xh,
                                              const float* __restrict__ mask, float* __restrict__ scal) {
  float pos = 0.f, dir = 0.f, ms = 0.f;
  for (int n = blockIdx.x * blockDim.x + TID; n < 65536; n += gridDim.x * blockDim.x) {
    const float* xp = x + (size_t)n * 36;
    const float* hp = xh + (size_t)n * 36;
    float a[36], h[36];
#pragma unroll
    for (int d4 = 0; d4 < 36; d4 += 4) {
      *(float4*)&a[d4] = *(const float4*)&xp[d4];
      *(float4*)&h[d4] = *(const float4*)&hp[d4];
    }
#pragma unroll
    for (int d = 0; d < 36; d++) {
      if (d < 21 || (d >= 27 && d < 30)) {
        float df = h[d] - a[d];
        float ad = fabsf(df);
        pos += (ad < 1.f) ? 0.5f * df * df : ad - 0.5f;
      }
    }
    float mL = mask[2 * (size_t)n], mR = mask[2 * (size_t)n + 1];
    const int vb[4] = {21, 24, 30, 33};
    float mv[4] = {mL, mL, mR, mR};
#pragma unroll
    for (int v = 0; v < 4; v++) {
      int o = vb[v];
      float ax = a[o], ay = a[o + 1], az = a[o + 2];
      float hx = h[o], hy = h[o + 1], hz = h[o + 2];
      float an = sqrtf(ax * ax + ay * ay + az * az) + 1e-8f;
      float hn = sqrtf(hx * hx + hy * hy + hz * hz) + 1e-8f;
      float cs = (ax * hx + ay * hy + az * hz) / (an * hn);
      dir += (1.f - cs) * mv[v];
    }
    ms += 2.f * (mL + mR);
  }
  __shared__ float rp[256], rd[256], rm[256];
  rp[TID] = pos; rd[TID] = dir; rm[TID] = ms;
  __syncthreads();
  for (int st = 128; st > 0; st >>= 1) {
    if (TID < st) { rp[TID] += rp[TID + st]; rd[TID] += rd[TID + st]; rm[TID] += rm[TID + st]; }
    __syncthreads();
  }
  if (TID == 0) {
    atomicAdd(&scal[1], rp[0]);
    atomicAdd(&scal[2], rd[0]);
    atomicAdd(&scal[3], rm[0]);
  }
}

__global__ __launch_bounds__(256) void finalize_k(const float* __restrict__ counts, const float* __restrict__ scal,
                                                  float* __restrict__ tail) {
  __shared__ float red[256];
  float s = 0.f;
  for (int j = TID; j < 1024; j += 256) {
    float avg = counts[j] * (1.f / 16384.f);
    s += avg * logf(avg + 1e-10f);
  }
  red[TID] = s;
  __syncthreads();
  for (int st = 128; st > 0; st >>= 1) {
    if (TID < st) red[TID] += red[TID + st];
    __syncthreads();
  }
  if (TID == 0) {
    tail[0] = 1.25f * scal[0] * (1.f / 2097152.f);
    tail[1] = expf(-red[0]);
    tail[2] = scal[1] * (1.f / 65536.f);
    tail[3] = scal[2] / fmaxf(scal[3], 1.f);
  }
}

// ================= host =================
extern "C" void kernel_launch(void* const* d_in, const int* in_sizes, int n_in,
                              void* d_out, int out_size, void* d_ws, size_t ws_size,
                              hipStream_t stream) {
  const float* x = (const float*)d_in[0];
  const float* mask = (const float*)d_in[1];
  const float* enc_in_w = (const float*)d_in[2];
  const float* enc_in_b = (const float*)d_in[3];
  const float* enc_gn1_g = (const float*)d_in[4];
  const float* enc_gn1_b = (const float*)d_in[5];
  const float* enc_c1_w = (const float*)d_in[6];
  const float* enc_c1_b = (const float*)d_in[7];
  const float* enc_gn2_g = (const float*)d_in[8];
  const float* enc_gn2_b = (const float*)d_in[9];
  const float* enc_c2_w = (const float*)d_in[10];
  const float* enc_c2_b = (const float*)d_in[11];
  const float* down_w = (const float*)d_in[12];
  const float* down_b = (const float*)d_in[13];
  const float* enc_out_w = (const float*)d_in[14];
  const float* enc_out_b = (const float*)d_in[15];
  const float* codebook = (const float*)d_in[16];
  const float* dec_in_w = (const float*)d_in[17];
  const float* dec_in_b = (const float*)d_in[18];
  const float* up_w = (const float*)d_in[19];
  const float* up_b = (const float*)d_in[20];
  const float* dec_gn1_g = (const float*)d_in[21];
  const float* dec_gn1_b = (const float*)d_in[22];
  const float* dec_c1_w = (const float*)d_in[23];
  const float* dec_c1_b = (const float*)d_in[24];
  const float* dec_gn2_g = (const float*)d_in[25];
  const float* dec_gn2_b = (const float*)d_in[26];
  const float* dec_c2_w = (const float*)d_in[27];
  const float* dec_c2_b = (const float*)d_in[28];
  const float* dec_out_w = (const float*)d_in[29];
  const float* dec_out_b = (const float*)d_in[30];

  char* W = (char*)d_ws;
  float* zE = (float*)(W + 0);                        // 8,388,608
  float* zQ = (float*)(W + 8388608);                  // 8,388,608
  int* codes = (int*)(W + 16777216);                  // 65,536
  float* counts = (float*)(W + 16842752);             // 4,096 (1024 f)
  float* scal = (float*)(W + 16846848);               // 32
  float* stats = (float*)(W + 16846880);              // 18 x 512 f = 36,864 B
  float* csq = (float*)(W + 16883744);                // 4,096
  float* wf_enc_in = (float*)(W + 16887840);          // 110,592
  float* wf_enc_c1 = (float*)(W + 16998432);          // 3,145,728
  float* wf_enc_c2 = (float*)(W + 20144160);          // 3,145,728
  float* wf_down = (float*)(W + 23289888);            // 2,097,152
  float* wf_enc_out = (float*)(W + 25387040);         // 131,072
  float* wf_dec_in = (float*)(W + 25518112);          // 131,072
  float* wf_dec_c1 = (float*)(W + 25649184);          // 3,145,728
  float* wf_dec_c2 = (float*)(W + 28794912);          // 3,145,728
  float* wf_dec_out = (float*)(W + 31940640);         // 147,456
  float* f0 = (float*)(W + 50331648);
  float* f2 = (float*)(W + 50331648 + (size_t)67108864);
  float* dech = (float*)(W + 50331648 + 2 * (size_t)67108864);

  dim3 blk(256);
  zero_k<<<dim3(41), blk, 0, stream>>>(counts, 1024 + 8 + 9216);
  perm_oik_iko<<<dim3(128), blk, 0, stream>>>(enc_in_w, wf_enc_in, 1, 256, 36, 3);
  perm_oik_iko<<<dim3(1024), blk, 0, stream>>>(enc_c1_w, wf_enc_c1, 4, 256, 256, 3);
  perm_oik_iko<<<dim3(1024), blk, 0, stream>>>(enc_c2_w, wf_enc_c2, 4, 256, 256, 3);
  perm_oik_iko<<<dim3(1024), blk, 0, stream>>>(down_w, wf_down, 1, 256, 256, 8);
  perm_oik_iko<<<dim3(128), blk, 0, stream>>>(enc_out_w, wf_enc_out, 1, 128, 256, 1);
  perm_oik_iko<<<dim3(128), blk, 0, stream>>>(dec_in_w, wf_dec_in, 1, 256, 128, 1);
  perm_oik_iko<<<dim3(1024), blk, 0, stream>>>(dec_c1_w, wf_dec_c1, 4, 256, 256, 3);
  perm_oik_iko<<<dim3(1024), blk, 0, stream>>>(dec_c2_w, wf_dec_c2, 4, 256, 256, 3);
  perm_decout<<<dim3(64), blk, 0, stream>>>(dec_out_w, wf_dec_out);
  csq_f32<<<dim3(4), blk, 0, stream>>>(codebook, csq);

  // ---- encoder (fp32), whole batch; stats slots 0..7 ----
  conv_in_k<<<dim3(NB * 32, 4), blk, 0, stream>>>(x, wf_enc_in, enc_in_b, f0, stats + 0 * 512);
  for (int i = 0; i < 4; i++) {
    float* sIn = stats + (2 * i) * 512;
    float* sMid = stats + (2 * i + 1) * 512;
    float* sOut = (i < 3) ? stats + (2 * i + 2) * 512 : nullptr;
    conv3_gn_k<<<dim3(NB * 8, 2), blk, 0, stream>>>(f0, sIn, enc_gn1_g + i * 256, enc_gn1_b + i * 256,
                                                    wf_enc_c1 + i * 196608, enc_c1_b + i * 256, nullptr, f2, sMid);
    conv3_gn_k<<<dim3(NB * 8, 2), blk, 0, stream>>>(f2, sMid, enc_gn2_g + i * 256, enc_gn2_b + i * 256,
                                                    wf_enc_c2 + i * 196608, enc_c2_b + i * 256, f0, f0, sOut);
  }
  conv_down_k<<<dim3(NB * 8, 4), blk, 0, stream>>>(f0, wf_down, down_b, f2);
  conv1x1_k<<<dim3(NB * 8, 2), blk, 0, stream>>>(f2, wf_enc_out, enc_out_b, zE, 256, 128);

  // ---- quantize (counts + float codes fused into epilogue) ----
  vq_tiled<<<dim3(256), blk, 0, stream>>>(zE, codebook, csq, codes, counts, (float*)d_out + 2359296);
  gather_k<<<dim3(512), blk, 0, stream>>>(codebook, codes, zE, zQ, &scal[0]);

  // ---- decoder (fp32), whole batch; stats slots 9..16 ----
  float* xhat = (float*)d_out;
  conv1x1_k<<<dim3(NB * 8, 4), blk, 0, stream>>>(zQ, wf_dec_in, dec_in_b, dech, 128, 256);
  conv_up_k<<<dim3(NB * 9, 4), blk, 0, stream>>>(dech, up_w, up_b, f0, stats + 9 * 512);
  for (int i = 0; i < 4; i++) {
    float* sIn = stats + (9 + 2 * i) * 512;
    float* sMid = stats + (10 + 2 * i) * 512;
    float* sOut = (i < 3) ? stats + (11 + 2 * i) * 512 : nullptr;
    conv3_gn_k<<<dim3(NB * 8, 2), blk, 0, stream>>>(f0, sIn, dec_gn1_g + i * 256, dec_gn1_b + i * 256,
                                                    wf_dec_c1 + i * 196608, dec_c1_b + i * 256, nullptr, f2, sMid);
    conv3_gn_k<<<dim3(NB * 8, 2), blk, 0, stream>>>(f2, sMid, dec_gn2_g + i * 256, dec_gn2_b + i * 256,
                                                    wf_dec_c2 + i * 196608, dec_c2_b + i * 256, f0, f0, sOut);
  }
  conv_out_k<<<dim3(NB * 32), blk, 0, stream>>>(f0, wf_dec_out, dec_out_b, xhat);

  // ---- losses / scalars ----
  loss_k<<<dim3(256), blk, 0, stream>>>(x, xhat, mask, scal);
  finalize_k<<<dim3(1), blk, 0, stream>>>(counts, scal, (float*)d_out + 2375680);
}